// Round 1
// 1225.882 us; speedup vs baseline: 2.9361x; 2.9361x over previous
//
#include <hip/hip_runtime.h>
#include <hip/hip_bf16.h>
#include <math.h>

// Problem constants
#define NH    16
#define NOPE  128
#define ROPED 64
#define VD    128
#define QLR   1536
#define IH    8
#define ID    128
#define TOPK  8
#define EPSF  1e-5f
#define B_    2
#define S_    2048
#define H_    2048

using bf16 = __hip_bfloat16;
typedef __attribute__((ext_vector_type(8))) short short8;
typedef __attribute__((ext_vector_type(4))) short short4v;
typedef __attribute__((ext_vector_type(4))) float f32x4;

#define GLOBAL_AS __attribute__((address_space(1)))
#define LDS_AS    __attribute__((address_space(3)))

__device__ __forceinline__ float b2f(bf16 v) { return __bfloat162float(v); }
__device__ __forceinline__ bf16 f2b(float v) { return __float2bfloat16(v); }
__device__ __forceinline__ float toF(float v) { return v; }
__device__ __forceinline__ float toF(bf16 v) { return __bfloat162float(v); }
__device__ __forceinline__ void stoC(float* p, float v) { *p = v; }
__device__ __forceinline__ void stoC(bf16* p, float v) { *p = __float2bfloat16(v); }

// ---------------------------------------------------------------------------
// Legacy fp32 tiled GEMM — kept ONLY for the gate projection (N=8), which
// must stay exact fp32 so top-k indices are stable.
// ---------------------------------------------------------------------------
template <typename AT, typename BT, typename OT>
__global__ __launch_bounds__(256) void gemm_k(const AT* __restrict__ A,
                                              const BT* __restrict__ Bw,
                                              OT* __restrict__ C,
                                              int M, int N, int K) {
    __shared__ float As[64][17];
    __shared__ float Bs[16][64];
    const int t  = threadIdx.x;
    const int tx = t & 15, ty = t >> 4;
    const int row0 = blockIdx.y * 64;
    const int col0 = blockIdx.x * 64;
    const int ar = t >> 2;
    const int ac = (t & 3) * 4;
    const int br = t >> 4;
    const int bc = (t & 15) * 4;

    float acc[4][4] = {};

    for (int k0 = 0; k0 < K; k0 += 16) {
        {
            const int gr = row0 + ar;
            if (gr < M) {
                const AT* ap = A + (size_t)gr * K + k0 + ac;
                As[ar][ac + 0] = toF(ap[0]);
                As[ar][ac + 1] = toF(ap[1]);
                As[ar][ac + 2] = toF(ap[2]);
                As[ar][ac + 3] = toF(ap[3]);
            } else {
                As[ar][ac + 0] = 0.f; As[ar][ac + 1] = 0.f;
                As[ar][ac + 2] = 0.f; As[ar][ac + 3] = 0.f;
            }
        }
        {
            const int gk = k0 + br;
            const BT* bp = Bw + (size_t)gk * N + col0 + bc;
#pragma unroll
            for (int i = 0; i < 4; i++) {
                const int gc = col0 + bc + i;
                Bs[br][bc + i] = (gk < K && gc < N) ? toF(bp[i]) : 0.f;
            }
        }
        __syncthreads();
#pragma unroll
        for (int kk = 0; kk < 16; kk++) {
            float a[4], b[4];
#pragma unroll
            for (int i = 0; i < 4; i++) a[i] = As[ty * 4 + i][kk];
#pragma unroll
            for (int j = 0; j < 4; j++) b[j] = Bs[kk][tx * 4 + j];
#pragma unroll
            for (int i = 0; i < 4; i++)
#pragma unroll
                for (int j = 0; j < 4; j++) acc[i][j] += a[i] * b[j];
        }
        __syncthreads();
    }

#pragma unroll
    for (int i = 0; i < 4; i++) {
        const int gr = row0 + ty * 4 + i;
        if (gr >= M) continue;
#pragma unroll
        for (int j = 0; j < 4; j++) {
            const int gc = col0 + tx * 4 + j;
            if (gc >= N) continue;
            stoC(C + (size_t)gr * N + gc, acc[i][j]);
        }
    }
}

// ---------------------------------------------------------------------------
// NEW: bf16 MFMA GEMM, m97 structure. C = A @ Bt^T where A is MxK bf16
// row-major and Bt is NxK bf16 row-major (weights pre-transposed).
// 128x128 tile, BK=32, 4 waves in 2x2, each wave 64x64 (4x4 16x16 frags).
// Staging: global_load_lds width 16, linear LDS (wave-uniform base+lane*16).
// Fragment layouts verified in this problem's attention kernel (m89/m120):
//   A/B frag: [idx = lane&15][k = (lane>>4)*8 + j]; C/D: col=lane&15,
//   row=(lane>>4)*4+reg.
// Requires: M%128==0, N%128==0, K%32==0 (true for all call sites).
// ---------------------------------------------------------------------------
template <typename OT>
__global__ __launch_bounds__(256) void gemm_bt_mfma_k(const bf16* __restrict__ A,
                                                      const bf16* __restrict__ Bt,
                                                      OT* __restrict__ C,
                                                      int M, int N, int K) {
    __shared__ bf16 As[128 * 32];
    __shared__ bf16 Bs[128 * 32];
    const int t = threadIdx.x;
    const int w = t >> 6;            // wave 0..3
    const int l = t & 63;
    const int col = l & 15;
    const int quad = l >> 4;
    const int wm = w >> 1, wn = w & 1;
    const int row0 = blockIdx.y * 128;
    const int col0 = blockIdx.x * 128;

    // Staging addresses: chunk c (0..7) = 16 rows x 32 cols = 1024B of LDS.
    // Wave w owns chunks {w, w+4}. Lane l -> row l>>2, col (l&3)*8 of chunk.
    const int rA = l >> 2;
    const int cA = (l & 3) * 8;
    const bf16* ga0 = A + (size_t)(row0 + w * 16 + rA) * K + cA;
    const bf16* ga1 = A + (size_t)(row0 + (4 + w) * 16 + rA) * K + cA;
    const bf16* gb0 = Bt + (size_t)(col0 + w * 16 + rA) * K + cA;
    const bf16* gb1 = Bt + (size_t)(col0 + (4 + w) * 16 + rA) * K + cA;
    bf16* lA0 = &As[w * 512];
    bf16* lA1 = &As[(4 + w) * 512];
    bf16* lB0 = &Bs[w * 512];
    bf16* lB1 = &Bs[(4 + w) * 512];

    f32x4 acc[4][4];
#pragma unroll
    for (int i = 0; i < 4; i++)
#pragma unroll
        for (int j = 0; j < 4; j++) acc[i][j] = (f32x4){0.f, 0.f, 0.f, 0.f};

    for (int k0 = 0; k0 < K; k0 += 32) {
        __syncthreads();   // all waves done reading As/Bs from prev iteration
        __builtin_amdgcn_global_load_lds((const GLOBAL_AS void*)(ga0 + k0),
                                         (LDS_AS void*)lA0, 16, 0, 0);
        __builtin_amdgcn_global_load_lds((const GLOBAL_AS void*)(ga1 + k0),
                                         (LDS_AS void*)lA1, 16, 0, 0);
        __builtin_amdgcn_global_load_lds((const GLOBAL_AS void*)(gb0 + k0),
                                         (LDS_AS void*)lB0, 16, 0, 0);
        __builtin_amdgcn_global_load_lds((const GLOBAL_AS void*)(gb1 + k0),
                                         (LDS_AS void*)lB1, 16, 0, 0);
        __syncthreads();   // compiler drains vmcnt(0) before s_barrier

        short8 af[4], bfr[4];
#pragma unroll
        for (int i = 0; i < 4; i++) {
            af[i]  = *(const short8*)&As[(wm * 64 + i * 16 + col) * 32 + quad * 8];
            bfr[i] = *(const short8*)&Bs[(wn * 64 + i * 16 + col) * 32 + quad * 8];
        }
#pragma unroll
        for (int i = 0; i < 4; i++)
#pragma unroll
            for (int j = 0; j < 4; j++)
                acc[i][j] = __builtin_amdgcn_mfma_f32_16x16x32_bf16(af[i], bfr[j], acc[i][j], 0, 0, 0);
    }

#pragma unroll
    for (int i = 0; i < 4; i++)
#pragma unroll
        for (int j = 0; j < 4; j++)
#pragma unroll
            for (int r = 0; r < 4; r++) {
                const int gr = row0 + wm * 64 + i * 16 + quad * 4 + r;
                const int gc = col0 + wn * 64 + j * 16 + col;
                stoC(C + (size_t)gr * N + gc, acc[i][j][r]);
            }
}

// ---------------------------------------------------------------------------
// NEW: elementwise fp32 -> bf16 cast (vectorized float4 -> 8B store).
// ---------------------------------------------------------------------------
__global__ __launch_bounds__(256) void cast_bf16_k(const float* __restrict__ X,
                                                   bf16* __restrict__ Y, int n4) {
    for (int i = blockIdx.x * 256 + threadIdx.x; i < n4; i += gridDim.x * 256) {
        const f32x4 v = ((const f32x4*)X)[i];
        short4v o;
#pragma unroll
        for (int j = 0; j < 4; j++) {
            bf16 b = f2b(v[j]);
            o[j] = *(short*)&b;
        }
        ((short4v*)Y)[i] = o;
    }
}

// ---------------------------------------------------------------------------
// NEW: tiled transpose-cast: W (KxN fp32) -> Wt (NxK bf16). Coalesced both
// directions via 32x33 LDS tile. Requires K%32==0, N%32==0.
// ---------------------------------------------------------------------------
__global__ __launch_bounds__(256) void transpose_cast_k(const float* __restrict__ W,
                                                        bf16* __restrict__ Wt,
                                                        int K, int N) {
    __shared__ float tile[32][33];
    const int t = threadIdx.x;
    const int tx = t & 31, ty = t >> 5;    // ty 0..7
    const int n0 = blockIdx.x * 32;
    const int k0 = blockIdx.y * 32;
#pragma unroll
    for (int i = 0; i < 4; i++)
        tile[ty + 8 * i][tx] = W[(size_t)(k0 + ty + 8 * i) * N + n0 + tx];
    __syncthreads();
#pragma unroll
    for (int i = 0; i < 4; i++)
        Wt[(size_t)(n0 + ty + 8 * i) * K + k0 + tx] = f2b(tile[tx][ty + 8 * i]);
}

// ---------------------------------------------------------------------------
// Row layernorm, now emitting bf16 (fp32 input no longer needed downstream).
// ---------------------------------------------------------------------------
__global__ __launch_bounds__(256) void layernorm_cast_k(const float* __restrict__ X,
                                                        const float* __restrict__ w,
                                                        const float* __restrict__ b,
                                                        bf16* __restrict__ Y,
                                                        int L) {
    __shared__ float r1[256], r2[256];
    const int row = blockIdx.x;
    const int t = threadIdx.x;
    const float* xp = X + (size_t)row * L;
    bf16* yp = Y + (size_t)row * L;
    float s1 = 0.f, s2 = 0.f;
    for (int j = t; j < L; j += 256) { const float v = xp[j]; s1 += v; s2 += v * v; }
    r1[t] = s1; r2[t] = s2; __syncthreads();
    for (int off = 128; off > 0; off >>= 1) {
        if (t < off) { r1[t] += r1[t + off]; r2[t] += r2[t + off]; }
        __syncthreads();
    }
    const float mu   = r1[0] / (float)L;
    const float var  = r2[0] / (float)L - mu * mu;
    const float rinv = rsqrtf(var + EPSF);
    for (int j = t; j < L; j += 256)
        yp[j] = f2b((xp[j] - mu) * rinv * w[j] + b[j]);
}

// ---------------------------------------------------------------------------
// In-place RoPE on qp (unchanged).
// ---------------------------------------------------------------------------
__global__ __launch_bounds__(256) void q_rope_k(bf16* __restrict__ qp) {
    const int total = B_ * S_ * NH * 32;
    for (int p = blockIdx.x * 256 + threadIdx.x; p < total; p += gridDim.x * 256) {
        const int j = p & 31;
        const int row = p >> 5;
        const int sr = row >> 4;
        const int s = sr & (S_ - 1);
        const size_t base = (size_t)row * 192 + 128 + 2 * j;
        const float xr = b2f(qp[base]);
        const float xi = b2f(qp[base + 1]);
        const float freq = powf(10000.f, -(float)(2 * j) / 64.f);
        const float ang = (float)s * freq;
        float sn, c; sincosf(ang, &sn, &c);
        qp[base]     = f2b(xr * c - xi * sn);
        qp[base + 1] = f2b(xr * sn + xi * c);
    }
}

// ---------------------------------------------------------------------------
// KV transform (unchanged).
// ---------------------------------------------------------------------------
__global__ __launch_bounds__(128) void kv_proc_k(bf16* __restrict__ kvc,
                                                 const float* __restrict__ knw,
                                                 const float* __restrict__ knb,
                                                 const float* __restrict__ Wkv,
                                                 bf16* __restrict__ Vb) {
    __shared__ float red[128];
    __shared__ float kvn[128];
    __shared__ float pe[64];
    const int idx = blockIdx.x;
    const int h = idx & (NH - 1);
    const int rest = idx >> 4;
    const int s = rest & (S_ - 1);
    const int b = rest >> 11;
    const size_t base = (size_t)idx * 192;
    const int t = threadIdx.x;

    const float v = b2f(kvc[base + 64 + t]);
    if (t < 64) pe[t] = b2f(kvc[base + t]);
    red[t] = v; __syncthreads();
    for (int off = 64; off > 0; off >>= 1) { if (t < off) red[t] += red[t + off]; __syncthreads(); }
    const float mu = red[0] / 128.f;
    __syncthreads();
    const float d = v - mu;
    red[t] = d * d; __syncthreads();
    for (int off = 64; off > 0; off >>= 1) { if (t < off) red[t] += red[t + off]; __syncthreads(); }
    const float rinv = rsqrtf(red[0] / 128.f + EPSF);
    kvn[t] = d * rinv * knw[t] + knb[t];
    __syncthreads();

    const size_t vbase = ((size_t)(b * NH + h) * S_ + s) * 128;
#pragma unroll
    for (int rep = 0; rep < 2; rep++) {
        const int n = t + rep * 128;
        float acc = 0.f;
        for (int k = 0; k < 128; k++) acc += kvn[k] * Wkv[k * 256 + n];
        if (n < 128) kvc[base + n] = f2b(acc);
        else         Vb[vbase + n - 128] = f2b(acc);
    }
    if (t < 32) {
        const float xr = pe[2 * t];
        const float xi = pe[2 * t + 1];
        const float freq = powf(10000.f, -(float)(2 * t) / 64.f);
        const float ang = (float)s * freq;
        float sn, c; sincosf(ang, &sn, &c);
        kvc[base + 128 + 2 * t]     = f2b(xr * c - xi * sn);
        kvc[base + 128 + 2 * t + 1] = f2b(xr * sn + xi * c);
    }
}

// ---------------------------------------------------------------------------
// Sparse branch (unchanged).
// ---------------------------------------------------------------------------
__global__ __launch_bounds__(256) void sparse_k(const float* __restrict__ gate,
                                                const float* __restrict__ ist,
                                                const float* __restrict__ Wsq,
                                                const float* __restrict__ Wsk,
                                                const float* __restrict__ Wsv,
                                                const float* __restrict__ Wio,
                                                float* __restrict__ io) {
    __shared__ float g[S_];
    __shared__ float sel[TOPK][ID];
    __shared__ float sq[TOPK][ID], sk[TOPK][ID], sv[TOPK][ID];
    __shared__ float sp[TOPK][TOPK];
    __shared__ float ms[ID];
    __shared__ float rv[256];
    __shared__ int ri[256];
    __shared__ int sidx[TOPK];
    const int bi = blockIdx.x;
    const int ih = bi % IH;
    const int b = bi / IH;
    const int t = threadIdx.x;

    for (int s = t; s < S_; s += 256) g[s] = gate[(size_t)(b * S_ + s) * IH + ih];
    __syncthreads();

    for (int r = 0; r < TOPK; r++) {
        float bv = -INFINITY; int bx = S_;
        for (int s = t; s < S_; s += 256) {
            const float v = g[s];
            if (v > bv) { bv = v; bx = s; }
        }
        rv[t] = bv; ri[t] = bx; __syncthreads();
        for (int off = 128; off > 0; off >>= 1) {
            if (t < off) {
                const float v2 = rv[t + off]; const int i2 = ri[t + off];
                if (v2 > rv[t] || (v2 == rv[t] && i2 < ri[t])) { rv[t] = v2; ri[t] = i2; }
            }
            __syncthreads();
        }
        if (t == 0) { sidx[r] = ri[0]; g[ri[0]] = -INFINITY; }
        __syncthreads();
    }

    for (int i = t; i < TOPK * ID; i += 256) {
        const int r = i >> 7, d = i & 127;
        sel[r][d] = ist[((size_t)(b * S_ + sidx[r]) * IH + ih) * ID + d];
    }
    __syncthreads();

    for (int i = t; i < TOPK * ID; i += 256) {
        const int r = i >> 7, n = i & 127;
        float aq = 0.f, ak = 0.f, av = 0.f;
        for (int k = 0; k < 128; k++) {
            const float s = sel[r][k];
            aq += s * Wsq[k * ID + n];
            ak += s * Wsk[k * ID + n];
            av += s * Wsv[k * ID + n];
        }
        sq[r][n] = aq; sk[r][n] = ak; sv[r][n] = av;
    }
    __syncthreads();

    if (t < TOPK * TOPK) {
        const int r = t >> 3, c = t & 7;
        float a = 0.f;
        for (int k = 0; k < 128; k++) a += sq[r][k] * sk[c][k];
        sp[r][c] = a * 0.08838834764831845f;
    }
    __syncthreads();

    if (t < TOPK) {
        float m = -INFINITY;
        for (int c = 0; c < 8; c++) m = fmaxf(m, sp[t][c]);
        float e[8]; float sum = 0.f;
        for (int c = 0; c < 8; c++) { e[c] = expf(sp[t][c] - m); sum += e[c]; }
        for (int c = 0; c < 8; c++) sp[t][c] = e[c] / sum;
    }
    __syncthreads();

    if (t < ID) {
        float acc = 0.f;
        for (int r = 0; r < 8; r++) {
            float so = 0.f;
            for (int c = 0; c < 8; c++) so += sp[r][c] * sv[c][t];
            acc += so;
        }
        ms[t] = acc * 0.125f;
    }
    __syncthreads();

    if (t < ID) {
        float acc = 0.f;
        for (int k = 0; k < 128; k++) acc += ms[k] * Wio[(size_t)k * H_ + t];
        io[((size_t)b * IH + ih) * ID + t] = acc;
    }
}

// ---------------------------------------------------------------------------
// MFMA flash attention (unchanged math), epilogue now writes bf16 so the
// final W_o projection can run on the matrix pipe.
// ---------------------------------------------------------------------------
__global__ __launch_bounds__(256) void attn_mfma_k(const bf16* __restrict__ Qp,
                                                   const bf16* __restrict__ Kc,
                                                   const bf16* __restrict__ Vb,
                                                   const float* __restrict__ io,
                                                   bf16* __restrict__ O) {
    __shared__ unsigned short Kt[32 * 200];   // K-tile, row stride 200 (pad)
    __shared__ unsigned short Vt[128 * 40];   // V-tile transposed, stride 40
    __shared__ unsigned short Ps[4 * 16 * 40];// per-wave P patch, stride 40
    __shared__ float io_s[128];

    const int qt = blockIdx.x, h = blockIdx.y, b = blockIdx.z;
    const int q0 = qt * 64;
    const int t = threadIdx.x;
    const int lane = t & 63;
    const int wq = t >> 6;            // wave id -> 16-query subtile
    const int col = lane & 15;        // n-index (key within tile / dv)
    const int quad = lane >> 4;       // 0..3

    if (t < 128) io_s[t] = io[((size_t)b * IH + (h >> 1)) * ID + t];

    short8 qfrag[6];
    {
        const int q = q0 + wq * 16 + col;
        const short8* qrow = (const short8*)(Qp + ((size_t)(b * S_ + q) * NH + h) * 192);
#pragma unroll
        for (int kc = 0; kc < 6; kc++) qfrag[kc] = qrow[kc * 4 + quad];
    }

    float m_r[4], l_r[4];
#pragma unroll
    for (int r = 0; r < 4; r++) { m_r[r] = -1e30f; l_r[r] = 0.f; }
    f32x4 accO[8];
#pragma unroll
    for (int nt = 0; nt < 8; nt++) accO[nt] = (f32x4){0.f, 0.f, 0.f, 0.f};

    const int nkt = qt * 2 + 2;
    const float scale = 0.07216878364870322f;  // 1/sqrt(192)

    for (int kt = 0; kt < nkt; kt++) {
        const int kt0 = kt * 32;
        __syncthreads();
        {
            const int kr = t >> 3;
            const int c0 = (t & 7) * 24;
            const short8* src = (const short8*)(Kc + ((size_t)(b * S_ + kt0 + kr) * NH + h) * 192 + c0);
            short8* dst = (short8*)&Kt[kr * 200 + c0];
            dst[0] = src[0]; dst[1] = src[1]; dst[2] = src[2];
        }
        {
            const int ki = t >> 3;
            const bf16* vrow = Vb + ((size_t)(b * NH + h) * S_ + kt0 + ki) * 128;
#pragma unroll
            for (int j = 0; j < 16; j++) {
                const int dv = (t & 7) + 8 * j;
                Vt[dv * 40 + ki] = *(const unsigned short*)(vrow + dv);
            }
        }
        __syncthreads();

        f32x4 s[2];
#pragma unroll
        for (int nt = 0; nt < 2; nt++) {
            f32x4 acc = (f32x4){0.f, 0.f, 0.f, 0.f};
#pragma unroll
            for (int kc = 0; kc < 6; kc++) {
                const short8 kf = *(const short8*)&Kt[(nt * 16 + col) * 200 + kc * 32 + quad * 8];
                acc = __builtin_amdgcn_mfma_f32_16x16x32_bf16(qfrag[kc], kf, acc, 0, 0, 0);
            }
            s[nt] = acc;
        }
#pragma unroll
        for (int nt = 0; nt < 2; nt++)
#pragma unroll
            for (int r = 0; r < 4; r++) {
                const int kg = kt0 + nt * 16 + col;
                const int qg = q0 + wq * 16 + quad * 4 + r;
                const float v = s[nt][r] * scale;
                s[nt][r] = (kg > qg) ? -1e30f : v;
            }
        float alpha[4];
#pragma unroll
        for (int r = 0; r < 4; r++) {
            float mt = fmaxf(s[0][r], s[1][r]);
            mt = fmaxf(mt, __shfl_xor(mt, 1));
            mt = fmaxf(mt, __shfl_xor(mt, 2));
            mt = fmaxf(mt, __shfl_xor(mt, 4));
            mt = fmaxf(mt, __shfl_xor(mt, 8));
            const float mn = fmaxf(m_r[r], mt);
            alpha[r] = __expf(m_r[r] - mn);
            m_r[r] = mn;
            const float p0 = __expf(s[0][r] - mn);
            const float p1 = __expf(s[1][r] - mn);
            s[0][r] = p0; s[1][r] = p1;
            float rs = p0 + p1;
            rs += __shfl_xor(rs, 1);
            rs += __shfl_xor(rs, 2);
            rs += __shfl_xor(rs, 4);
            rs += __shfl_xor(rs, 8);
            l_r[r] = l_r[r] * alpha[r] + rs;
        }
        {
            unsigned short* pw = &Ps[wq * 640];
#pragma unroll
            for (int nt = 0; nt < 2; nt++)
#pragma unroll
                for (int r = 0; r < 4; r++) {
                    bf16 hv = f2b(s[nt][r]);
                    pw[(quad * 4 + r) * 40 + nt * 16 + col] = *(unsigned short*)&hv;
                }
        }
        const short8 pfrag = *(const short8*)&Ps[wq * 640 + col * 40 + quad * 8];
#pragma unroll
        for (int nt = 0; nt < 8; nt++)
#pragma unroll
            for (int r = 0; r < 4; r++) accO[nt][r] *= alpha[r];
#pragma unroll
        for (int nt = 0; nt < 8; nt++) {
            const short8 vf = *(const short8*)&Vt[(nt * 16 + col) * 40 + quad * 8];
            accO[nt] = __builtin_amdgcn_mfma_f32_16x16x32_bf16(pfrag, vf, accO[nt], 0, 0, 0);
        }
    }

    float rinv[4];
#pragma unroll
    for (int r = 0; r < 4; r++) rinv[r] = 1.f / l_r[r];
#pragma unroll
    for (int nt = 0; nt < 8; nt++) {
        const int dv = nt * 16 + col;
        const float iov = io_s[dv];
#pragma unroll
        for (int r = 0; r < 4; r++) {
            const int q = q0 + wq * 16 + quad * 4 + r;
            O[((size_t)(b * S_ + q) * NH + h) * VD + dv] = f2b(accO[nt][r] * rinv[r] + iov);
        }
    }
}

// ---------------------------------------------------------------------------
// Workspace lifetime plan (stays within the proven ~100.8 MB):
//   rbig  @ 0        (33.5MB): cq fp32 -> ist fp32 -> attn_bf16
//   qp    @ 32MB     (25.2MB)
//   kvc   @ 56MB     (25.2MB): cq_bf16 (pre-kvc) -> kvc
//   Vb/Wt @ 80MB     (16.8MB): Wt transposes (pre-kv_proc) -> Vb -> Wt(W_o)
//   gate  @ 96MB, iob after
//   x_bf16 lives in d_out (dead before the final GEMM writes out).
// ---------------------------------------------------------------------------
extern "C" void kernel_launch(void* const* d_in, const int* in_sizes, int n_in,
                              void* d_out, int out_size, void* d_ws, size_t ws_size,
                              hipStream_t stream) {
    const float* x      = (const float*)d_in[0];
    const float* W_cq   = (const float*)d_in[1];
    const float* qn_w   = (const float*)d_in[2];
    const float* qn_b   = (const float*)d_in[3];
    const float* W_q    = (const float*)d_in[4];
    const float* W_ckv  = (const float*)d_in[5];
    const float* kvn_w  = (const float*)d_in[6];
    const float* kvn_b  = (const float*)d_in[7];
    const float* W_kv   = (const float*)d_in[8];
    const float* W_o    = (const float*)d_in[9];
    const float* W_ip   = (const float*)d_in[10];
    const float* W_ig   = (const float*)d_in[11];
    const float* W_sq   = (const float*)d_in[12];
    const float* W_sk   = (const float*)d_in[13];
    const float* W_sv   = (const float*)d_in[14];
    const float* W_io   = (const float*)d_in[15];
    float* out = (float*)d_out;

    const int M = B_ * S_;

    char* wsb = (char*)d_ws;
    float* rbig  = (float*)wsb;
    bf16*  qp    = (bf16*)(wsb + 33554432);
    bf16*  kvc   = (bf16*)(wsb + 58720256);
    bf16*  cqb   = (bf16*)(wsb + 58720256);   // alias kvc (dead before kvc)
    bf16*  Vb    = (bf16*)(wsb + 83886080);
    bf16*  Wt    = (bf16*)(wsb + 83886080);   // alias Vb (disjoint lifetimes)
    float* gate  = (float*)(wsb + 100663296);
    float* iob   = (float*)(wsb + 100794368);
    float* cq    = rbig;
    float* ist   = rbig;
    bf16*  attnb = (bf16*)rbig;
    bf16*  xb    = (bf16*)d_out;              // x_bf16 in output buffer

    dim3 blk(256);

    // Stage 0: casts
    cast_bf16_k<<<dim3(2048), blk, 0, stream>>>(x, xb, M * H_ / 4);

    // qc = LN(x @ W_cq)
    transpose_cast_k<<<dim3(QLR / 32, H_ / 32), blk, 0, stream>>>(W_cq, Wt, H_, QLR);
    gemm_bt_mfma_k<float><<<dim3(QLR / 128, M / 128), blk, 0, stream>>>(xb, Wt, cq, M, QLR, H_);
    layernorm_cast_k<<<dim3(M), blk, 0, stream>>>(cq, qn_w, qn_b, cqb, QLR);

    // qp = qc @ W_q
    transpose_cast_k<<<dim3(3072 / 32, QLR / 32), blk, 0, stream>>>(W_q, Wt, QLR, 3072);
    gemm_bt_mfma_k<bf16><<<dim3(3072 / 128, M / 128), blk, 0, stream>>>(cqb, Wt, qp, M, 3072, QLR);

    // kvc = x @ W_ckv
    transpose_cast_k<<<dim3(3072 / 32, H_ / 32), blk, 0, stream>>>(W_ckv, Wt, H_, 3072);
    gemm_bt_mfma_k<bf16><<<dim3(3072 / 128, M / 128), blk, 0, stream>>>(xb, Wt, kvc, M, 3072, H_);

    // ist = x @ W_ip (fp32 out for sparse branch)
    transpose_cast_k<<<dim3(1024 / 32, H_ / 32), blk, 0, stream>>>(W_ip, Wt, H_, 1024);
    gemm_bt_mfma_k<float><<<dim3(1024 / 128, M / 128), blk, 0, stream>>>(xb, Wt, ist, M, IH * ID, H_);

    // gate = x @ W_ig — EXACT fp32 (top-k index stability)
    gemm_k<float, float, float><<<dim3(1, M / 64), blk, 0, stream>>>(x, W_ig, gate, M, IH, H_);

    q_rope_k<<<dim3(2048), blk, 0, stream>>>(qp);
    kv_proc_k<<<dim3(B_ * S_ * NH), dim3(128), 0, stream>>>(kvc, kvn_w, kvn_b, W_kv, Vb);
    sparse_k<<<dim3(B_ * IH), blk, 0, stream>>>(gate, ist, W_sq, W_sk, W_sv, W_io, iob);

    // attention -> bf16 attn (rbig; ist already consumed)
    attn_mfma_k<<<dim3(S_ / 64, NH, B_), blk, 0, stream>>>(qp, kvc, Vb, iob, attnb);

    // out = attn @ W_o (Vb dead -> reuse for W_o^T)
    transpose_cast_k<<<dim3(H_ / 32, H_ / 32), blk, 0, stream>>>(W_o, Wt, H_, H_);
    gemm_bt_mfma_k<float><<<dim3(H_ / 128, M / 128), blk, 0, stream>>>(attnb, Wt, out, M, H_, H_);
}

// Round 3
// 860.396 us; speedup vs baseline: 4.1833x; 1.4248x over previous
//
#include <hip/hip_runtime.h>
#include <hip/hip_bf16.h>
#include <math.h>

// Problem constants
#define NH    16
#define NOPE  128
#define ROPED 64
#define VD    128
#define QLR   1536
#define IH    8
#define ID    128
#define TOPK  8
#define EPSF  1e-5f
#define B_    2
#define S_    2048
#define H_    2048

using bf16 = __hip_bfloat16;
typedef __attribute__((ext_vector_type(8))) short short8;
typedef __attribute__((ext_vector_type(4))) short short4v;
typedef __attribute__((ext_vector_type(4))) float f32x4;

#define GLOBAL_AS __attribute__((address_space(1)))
#define LDS_AS    __attribute__((address_space(3)))

__device__ __forceinline__ float b2f(bf16 v) { return __bfloat162float(v); }
__device__ __forceinline__ bf16 f2b(float v) { return __float2bfloat16(v); }
__device__ __forceinline__ float toF(float v) { return v; }
__device__ __forceinline__ float toF(bf16 v) { return __bfloat162float(v); }
__device__ __forceinline__ void stoC(float* p, float v) { *p = v; }
__device__ __forceinline__ void stoC(bf16* p, float v) { *p = __float2bfloat16(v); }

// ---------------------------------------------------------------------------
// Legacy fp32 tiled GEMM — kept ONLY for the gate projection (N=8), which
// must stay exact fp32 so top-k indices are stable.
// ---------------------------------------------------------------------------
template <typename AT, typename BT, typename OT>
__global__ __launch_bounds__(256) void gemm_k(const AT* __restrict__ A,
                                              const BT* __restrict__ Bw,
                                              OT* __restrict__ C,
                                              int M, int N, int K) {
    __shared__ float As[64][17];
    __shared__ float Bs[16][64];
    const int t  = threadIdx.x;
    const int tx = t & 15, ty = t >> 4;
    const int row0 = blockIdx.y * 64;
    const int col0 = blockIdx.x * 64;
    const int ar = t >> 2;
    const int ac = (t & 3) * 4;
    const int br = t >> 4;
    const int bc = (t & 15) * 4;

    float acc[4][4] = {};

    for (int k0 = 0; k0 < K; k0 += 16) {
        {
            const int gr = row0 + ar;
            if (gr < M) {
                const AT* ap = A + (size_t)gr * K + k0 + ac;
                As[ar][ac + 0] = toF(ap[0]);
                As[ar][ac + 1] = toF(ap[1]);
                As[ar][ac + 2] = toF(ap[2]);
                As[ar][ac + 3] = toF(ap[3]);
            } else {
                As[ar][ac + 0] = 0.f; As[ar][ac + 1] = 0.f;
                As[ar][ac + 2] = 0.f; As[ar][ac + 3] = 0.f;
            }
        }
        {
            const int gk = k0 + br;
            const BT* bp = Bw + (size_t)gk * N + col0 + bc;
#pragma unroll
            for (int i = 0; i < 4; i++) {
                const int gc = col0 + bc + i;
                Bs[br][bc + i] = (gk < K && gc < N) ? toF(bp[i]) : 0.f;
            }
        }
        __syncthreads();
#pragma unroll
        for (int kk = 0; kk < 16; kk++) {
            float a[4], b[4];
#pragma unroll
            for (int i = 0; i < 4; i++) a[i] = As[ty * 4 + i][kk];
#pragma unroll
            for (int j = 0; j < 4; j++) b[j] = Bs[kk][tx * 4 + j];
#pragma unroll
            for (int i = 0; i < 4; i++)
#pragma unroll
                for (int j = 0; j < 4; j++) acc[i][j] += a[i] * b[j];
        }
        __syncthreads();
    }

#pragma unroll
    for (int i = 0; i < 4; i++) {
        const int gr = row0 + ty * 4 + i;
        if (gr >= M) continue;
#pragma unroll
        for (int j = 0; j < 4; j++) {
            const int gc = col0 + tx * 4 + j;
            if (gc >= N) continue;
            stoC(C + (size_t)gr * N + gc, acc[i][j]);
        }
    }
}

// ---------------------------------------------------------------------------
// bf16 MFMA GEMM, m97 structure (verified R1).
// C = A @ Bt^T, A MxK bf16 row-major, Bt NxK bf16 row-major.
// ---------------------------------------------------------------------------
template <typename OT>
__global__ __launch_bounds__(256) void gemm_bt_mfma_k(const bf16* __restrict__ A,
                                                      const bf16* __restrict__ Bt,
                                                      OT* __restrict__ C,
                                                      int M, int N, int K) {
    __shared__ bf16 As[128 * 32];
    __shared__ bf16 Bs[128 * 32];
    const int t = threadIdx.x;
    const int w = t >> 6;
    const int l = t & 63;
    const int col = l & 15;
    const int quad = l >> 4;
    const int wm = w >> 1, wn = w & 1;
    const int row0 = blockIdx.y * 128;
    const int col0 = blockIdx.x * 128;

    const int rA = l >> 2;
    const int cA = (l & 3) * 8;
    const bf16* ga0 = A + (size_t)(row0 + w * 16 + rA) * K + cA;
    const bf16* ga1 = A + (size_t)(row0 + (4 + w) * 16 + rA) * K + cA;
    const bf16* gb0 = Bt + (size_t)(col0 + w * 16 + rA) * K + cA;
    const bf16* gb1 = Bt + (size_t)(col0 + (4 + w) * 16 + rA) * K + cA;
    bf16* lA0 = &As[w * 512];
    bf16* lA1 = &As[(4 + w) * 512];
    bf16* lB0 = &Bs[w * 512];
    bf16* lB1 = &Bs[(4 + w) * 512];

    f32x4 acc[4][4];
#pragma unroll
    for (int i = 0; i < 4; i++)
#pragma unroll
        for (int j = 0; j < 4; j++) acc[i][j] = (f32x4){0.f, 0.f, 0.f, 0.f};

    for (int k0 = 0; k0 < K; k0 += 32) {
        __syncthreads();
        __builtin_amdgcn_global_load_lds((const GLOBAL_AS void*)(ga0 + k0),
                                         (LDS_AS void*)lA0, 16, 0, 0);
        __builtin_amdgcn_global_load_lds((const GLOBAL_AS void*)(ga1 + k0),
                                         (LDS_AS void*)lA1, 16, 0, 0);
        __builtin_amdgcn_global_load_lds((const GLOBAL_AS void*)(gb0 + k0),
                                         (LDS_AS void*)lB0, 16, 0, 0);
        __builtin_amdgcn_global_load_lds((const GLOBAL_AS void*)(gb1 + k0),
                                         (LDS_AS void*)lB1, 16, 0, 0);
        __syncthreads();

        short8 af[4], bfr[4];
#pragma unroll
        for (int i = 0; i < 4; i++) {
            af[i]  = *(const short8*)&As[(wm * 64 + i * 16 + col) * 32 + quad * 8];
            bfr[i] = *(const short8*)&Bs[(wn * 64 + i * 16 + col) * 32 + quad * 8];
        }
#pragma unroll
        for (int i = 0; i < 4; i++)
#pragma unroll
            for (int j = 0; j < 4; j++)
                acc[i][j] = __builtin_amdgcn_mfma_f32_16x16x32_bf16(af[i], bfr[j], acc[i][j], 0, 0, 0);
    }

#pragma unroll
    for (int i = 0; i < 4; i++)
#pragma unroll
        for (int j = 0; j < 4; j++)
#pragma unroll
            for (int r = 0; r < 4; r++) {
                const int gr = row0 + wm * 64 + i * 16 + quad * 4 + r;
                const int gc = col0 + wn * 64 + j * 16 + col;
                stoC(C + (size_t)gr * N + gc, acc[i][j][r]);
            }
}

// ---------------------------------------------------------------------------
// kv matmul on MFMA with scatter epilogue. A = kvn [65536 x 128] bf16,
// Bt = WkvT [256 x 128] bf16. Out col<128 -> kvc[row*192+col] (k_nope);
// col>=128 -> Vb. Row = ((b*S_+s)*NH)+h.
// ---------------------------------------------------------------------------
__global__ __launch_bounds__(256) void gemm_kv_k(const bf16* __restrict__ A,
                                                 const bf16* __restrict__ Bt,
                                                 bf16* __restrict__ kvc,
                                                 bf16* __restrict__ Vb) {
    __shared__ bf16 As[128 * 32];
    __shared__ bf16 Bs[128 * 32];
    const int K = 128;
    const int t = threadIdx.x;
    const int w = t >> 6;
    const int l = t & 63;
    const int col = l & 15;
    const int quad = l >> 4;
    const int wm = w >> 1, wn = w & 1;
    const int row0 = blockIdx.y * 128;
    const int col0 = blockIdx.x * 128;

    const int rA = l >> 2;
    const int cA = (l & 3) * 8;
    const bf16* ga0 = A + (size_t)(row0 + w * 16 + rA) * K + cA;
    const bf16* ga1 = A + (size_t)(row0 + (4 + w) * 16 + rA) * K + cA;
    const bf16* gb0 = Bt + (size_t)(col0 + w * 16 + rA) * K + cA;
    const bf16* gb1 = Bt + (size_t)(col0 + (4 + w) * 16 + rA) * K + cA;
    bf16* lA0 = &As[w * 512];
    bf16* lA1 = &As[(4 + w) * 512];
    bf16* lB0 = &Bs[w * 512];
    bf16* lB1 = &Bs[(4 + w) * 512];

    f32x4 acc[4][4];
#pragma unroll
    for (int i = 0; i < 4; i++)
#pragma unroll
        for (int j = 0; j < 4; j++) acc[i][j] = (f32x4){0.f, 0.f, 0.f, 0.f};

    for (int k0 = 0; k0 < K; k0 += 32) {
        __syncthreads();
        __builtin_amdgcn_global_load_lds((const GLOBAL_AS void*)(ga0 + k0),
                                         (LDS_AS void*)lA0, 16, 0, 0);
        __builtin_amdgcn_global_load_lds((const GLOBAL_AS void*)(ga1 + k0),
                                         (LDS_AS void*)lA1, 16, 0, 0);
        __builtin_amdgcn_global_load_lds((const GLOBAL_AS void*)(gb0 + k0),
                                         (LDS_AS void*)lB0, 16, 0, 0);
        __builtin_amdgcn_global_load_lds((const GLOBAL_AS void*)(gb1 + k0),
                                         (LDS_AS void*)lB1, 16, 0, 0);
        __syncthreads();

        short8 af[4], bfr[4];
#pragma unroll
        for (int i = 0; i < 4; i++) {
            af[i]  = *(const short8*)&As[(wm * 64 + i * 16 + col) * 32 + quad * 8];
            bfr[i] = *(const short8*)&Bs[(wn * 64 + i * 16 + col) * 32 + quad * 8];
        }
#pragma unroll
        for (int i = 0; i < 4; i++)
#pragma unroll
            for (int j = 0; j < 4; j++)
                acc[i][j] = __builtin_amdgcn_mfma_f32_16x16x32_bf16(af[i], bfr[j], acc[i][j], 0, 0, 0);
    }

#pragma unroll
    for (int i = 0; i < 4; i++)
#pragma unroll
        for (int j = 0; j < 4; j++)
#pragma unroll
            for (int r = 0; r < 4; r++) {
                const int gr = row0 + wm * 64 + i * 16 + quad * 4 + r;
                const int gc = col0 + wn * 64 + j * 16 + col;
                const int bb = gr >> 15;
                const int ss = (gr >> 4) & (S_ - 1);
                const int hh = gr & (NH - 1);
                const bf16 v = f2b(acc[i][j][r]);
                if (gc < 128) kvc[(size_t)gr * 192 + gc] = v;
                else Vb[(((size_t)(bb * NH + hh)) * S_ + ss) * 128 + (gc - 128)] = v;
            }
}

// ---------------------------------------------------------------------------
// Wave-per-row LN of kv_nope -> bf16 kvn, plus RoPE of k_pe written to
// kvc cols 128..191 (k_nope cols 0..127 filled later by gemm_kv_k).
// ---------------------------------------------------------------------------
__global__ __launch_bounds__(256) void kv_ln_k(bf16* __restrict__ kvc,
                                               const float* __restrict__ knw,
                                               const float* __restrict__ knb,
                                               bf16* __restrict__ kvn) {
    const int idx = blockIdx.x * 4 + (threadIdx.x >> 6);   // row 0..65535
    const int lane = threadIdx.x & 63;
    const int s = (idx >> 4) & (S_ - 1);
    const size_t base = (size_t)idx * 192;

    const float v0 = b2f(kvc[base + 64 + lane]);
    const float v1 = b2f(kvc[base + 128 + lane]);
    float xr = 0.f, xi = 0.f;
    if (lane < 32) { xr = b2f(kvc[base + 2 * lane]); xi = b2f(kvc[base + 2 * lane + 1]); }

    float s1 = v0 + v1, s2 = v0 * v0 + v1 * v1;
#pragma unroll
    for (int off = 32; off > 0; off >>= 1) {
        s1 += __shfl_xor(s1, off);
        s2 += __shfl_xor(s2, off);
    }
    const float mu = s1 * (1.f / 128.f);
    const float rinv = rsqrtf(s2 * (1.f / 128.f) - mu * mu + EPSF);
    kvn[(size_t)idx * 128 + lane]      = f2b((v0 - mu) * rinv * knw[lane] + knb[lane]);
    kvn[(size_t)idx * 128 + lane + 64] = f2b((v1 - mu) * rinv * knw[lane + 64] + knb[lane + 64]);

    if (lane < 32) {
        const float freq = powf(10000.f, -(float)(2 * lane) / 64.f);
        const float ang = (float)s * freq;
        float sn, c; sincosf(ang, &sn, &c);
        kvc[base + 128 + 2 * lane]     = f2b(xr * c - xi * sn);
        kvc[base + 128 + 2 * lane + 1] = f2b(xr * sn + xi * c);
    }
}

// ---------------------------------------------------------------------------
// Elementwise fp32 -> bf16 cast.
// ---------------------------------------------------------------------------
__global__ __launch_bounds__(256) void cast_bf16_k(const float* __restrict__ X,
                                                   bf16* __restrict__ Y, int n4) {
    for (int i = blockIdx.x * 256 + threadIdx.x; i < n4; i += gridDim.x * 256) {
        const f32x4 v = ((const f32x4*)X)[i];
        short4v o;
#pragma unroll
        for (int j = 0; j < 4; j++) {
            bf16 b = f2b(v[j]);
            o[j] = *(short*)&b;
        }
        ((short4v*)Y)[i] = o;
    }
}

// ---------------------------------------------------------------------------
// Tiled transpose-cast: W (KxN fp32) -> Wt (NxK bf16).
// ---------------------------------------------------------------------------
__global__ __launch_bounds__(256) void transpose_cast_k(const float* __restrict__ W,
                                                        bf16* __restrict__ Wt,
                                                        int K, int N) {
    __shared__ float tile[32][33];
    const int t = threadIdx.x;
    const int tx = t & 31, ty = t >> 5;
    const int n0 = blockIdx.x * 32;
    const int k0 = blockIdx.y * 32;
#pragma unroll
    for (int i = 0; i < 4; i++)
        tile[ty + 8 * i][tx] = W[(size_t)(k0 + ty + 8 * i) * N + n0 + tx];
    __syncthreads();
#pragma unroll
    for (int i = 0; i < 4; i++)
        Wt[(size_t)(n0 + ty + 8 * i) * K + k0 + tx] = f2b(tile[tx][ty + 8 * i]);
}

// ---------------------------------------------------------------------------
// Row layernorm emitting bf16.
// ---------------------------------------------------------------------------
__global__ __launch_bounds__(256) void layernorm_cast_k(const float* __restrict__ X,
                                                        const float* __restrict__ w,
                                                        const float* __restrict__ b,
                                                        bf16* __restrict__ Y,
                                                        int L) {
    __shared__ float r1[256], r2[256];
    const int row = blockIdx.x;
    const int t = threadIdx.x;
    const float* xp = X + (size_t)row * L;
    bf16* yp = Y + (size_t)row * L;
    float s1 = 0.f, s2 = 0.f;
    for (int j = t; j < L; j += 256) { const float v = xp[j]; s1 += v; s2 += v * v; }
    r1[t] = s1; r2[t] = s2; __syncthreads();
    for (int off = 128; off > 0; off >>= 1) {
        if (t < off) { r1[t] += r1[t + off]; r2[t] += r2[t + off]; }
        __syncthreads();
    }
    const float mu   = r1[0] / (float)L;
    const float var  = r2[0] / (float)L - mu * mu;
    const float rinv = rsqrtf(var + EPSF);
    for (int j = t; j < L; j += 256)
        yp[j] = f2b((xp[j] - mu) * rinv * w[j] + b[j]);
}

// ---------------------------------------------------------------------------
// In-place RoPE on qp.
// ---------------------------------------------------------------------------
__global__ __launch_bounds__(256) void q_rope_k(bf16* __restrict__ qp) {
    const int total = B_ * S_ * NH * 32;
    for (int p = blockIdx.x * 256 + threadIdx.x; p < total; p += gridDim.x * 256) {
        const int j = p & 31;
        const int row = p >> 5;
        const int sr = row >> 4;
        const int s = sr & (S_ - 1);
        const size_t base = (size_t)row * 192 + 128 + 2 * j;
        const float xr = b2f(qp[base]);
        const float xi = b2f(qp[base + 1]);
        const float freq = powf(10000.f, -(float)(2 * j) / 64.f);
        const float ang = (float)s * freq;
        float sn, c; sincosf(ang, &sn, &c);
        qp[base]     = f2b(xr * c - xi * sn);
        qp[base + 1] = f2b(xr * sn + xi * c);
    }
}

// ---------------------------------------------------------------------------
// Sparse branch (unchanged).
// ---------------------------------------------------------------------------
__global__ __launch_bounds__(256) void sparse_k(const float* __restrict__ gate,
                                                const float* __restrict__ ist,
                                                const float* __restrict__ Wsq,
                                                const float* __restrict__ Wsk,
                                                const float* __restrict__ Wsv,
                                                const float* __restrict__ Wio,
                                                float* __restrict__ io) {
    __shared__ float g[S_];
    __shared__ float sel[TOPK][ID];
    __shared__ float sq[TOPK][ID], sk[TOPK][ID], sv[TOPK][ID];
    __shared__ float sp[TOPK][TOPK];
    __shared__ float ms[ID];
    __shared__ float rv[256];
    __shared__ int ri[256];
    __shared__ int sidx[TOPK];
    const int bi = blockIdx.x;
    const int ih = bi % IH;
    const int b = bi / IH;
    const int t = threadIdx.x;

    for (int s = t; s < S_; s += 256) g[s] = gate[(size_t)(b * S_ + s) * IH + ih];
    __syncthreads();

    for (int r = 0; r < TOPK; r++) {
        float bv = -INFINITY; int bx = S_;
        for (int s = t; s < S_; s += 256) {
            const float v = g[s];
            if (v > bv) { bv = v; bx = s; }
        }
        rv[t] = bv; ri[t] = bx; __syncthreads();
        for (int off = 128; off > 0; off >>= 1) {
            if (t < off) {
                const float v2 = rv[t + off]; const int i2 = ri[t + off];
                if (v2 > rv[t] || (v2 == rv[t] && i2 < ri[t])) { rv[t] = v2; ri[t] = i2; }
            }
            __syncthreads();
        }
        if (t == 0) { sidx[r] = ri[0]; g[ri[0]] = -INFINITY; }
        __syncthreads();
    }

    for (int i = t; i < TOPK * ID; i += 256) {
        const int r = i >> 7, d = i & 127;
        sel[r][d] = ist[((size_t)(b * S_ + sidx[r]) * IH + ih) * ID + d];
    }
    __syncthreads();

    for (int i = t; i < TOPK * ID; i += 256) {
        const int r = i >> 7, n = i & 127;
        float aq = 0.f, ak = 0.f, av = 0.f;
        for (int k = 0; k < 128; k++) {
            const float s = sel[r][k];
            aq += s * Wsq[k * ID + n];
            ak += s * Wsk[k * ID + n];
            av += s * Wsv[k * ID + n];
        }
        sq[r][n] = aq; sk[r][n] = ak; sv[r][n] = av;
    }
    __syncthreads();

    if (t < TOPK * TOPK) {
        const int r = t >> 3, c = t & 7;
        float a = 0.f;
        for (int k = 0; k < 128; k++) a += sq[r][k] * sk[c][k];
        sp[r][c] = a * 0.08838834764831845f;
    }
    __syncthreads();

    if (t < TOPK) {
        float m = -INFINITY;
        for (int c = 0; c < 8; c++) m = fmaxf(m, sp[t][c]);
        float e[8]; float sum = 0.f;
        for (int c = 0; c < 8; c++) { e[c] = expf(sp[t][c] - m); sum += e[c]; }
        for (int c = 0; c < 8; c++) sp[t][c] = e[c] / sum;
    }
    __syncthreads();

    if (t < ID) {
        float acc = 0.f;
        for (int r = 0; r < 8; r++) {
            float so = 0.f;
            for (int c = 0; c < 8; c++) so += sp[r][c] * sv[c][t];
            acc += so;
        }
        ms[t] = acc * 0.125f;
    }
    __syncthreads();

    if (t < ID) {
        float acc = 0.f;
        for (int k = 0; k < 128; k++) acc += ms[k] * Wio[(size_t)k * H_ + t];
        io[((size_t)b * IH + ih) * ID + t] = acc;
    }
}

// ---------------------------------------------------------------------------
// MFMA flash attention v2 (fixed):
//  - Each block processes the q-tile PAIR (i, 31-i): uniform 33 K-tiles per
//    block -> no causal tail imbalance. Grid (16, NH, B_) = 512 blocks.
//  - KVBLK = 64: half the barriers/softmax/P roundtrips per key.
//  - s_setprio around MFMA clusters (T5).
//  - Bijective chunked XCD swizzle (512 = 8 * 64).
// FIXES vs failed R2: grid.x 32->16 (decode assumed 16); K-tile staging now
// covers all 192 cols (6 short8 per thread, was 3).
// ---------------------------------------------------------------------------
__global__ __launch_bounds__(256) void attn_mfma_k(const bf16* __restrict__ Qp,
                                                   const bf16* __restrict__ Kc,
                                                   const bf16* __restrict__ Vb,
                                                   const float* __restrict__ io,
                                                   bf16* __restrict__ O) {
    __shared__ unsigned short Kt[64 * 200];    // 64 keys x 192 dims (+8 pad)
    __shared__ unsigned short Vt[128 * 72];    // V^T: 128 dv x 64 keys (+8 pad)
    __shared__ unsigned short Ps[4 * 16 * 72]; // per-wave P patch 16q x 64k (+8)
    __shared__ float io_s[128];

    // Chunked XCD swizzle (bijective: 512 = 8 * 64)
    const int lin = blockIdx.x + 16 * blockIdx.y + 256 * blockIdx.z;
    const int swz = (lin & 7) * 64 + (lin >> 3);
    const int pairi = swz & 15;
    const int h = (swz >> 4) & 15;
    const int b = swz >> 8;

    const int t = threadIdx.x;
    const int lane = t & 63;
    const int wq = t >> 6;
    const int col = lane & 15;
    const int quad = lane >> 4;

    if (t < 128) io_s[t] = io[((size_t)b * IH + (h >> 1)) * ID + t];

    const float scale = 0.07216878364870322f;  // 1/sqrt(192)

#pragma unroll 1
    for (int ti = 0; ti < 2; ti++) {
        const int qt = (ti == 0) ? pairi : 31 - pairi;
        const int q0 = qt * 64;

        // Q fragments for this tile
        short8 qfrag[6];
        {
            const int q = q0 + wq * 16 + col;
            const short8* qrow = (const short8*)(Qp + ((size_t)(b * S_ + q) * NH + h) * 192);
#pragma unroll
            for (int kc = 0; kc < 6; kc++) qfrag[kc] = qrow[kc * 4 + quad];
        }

        float m_r[4], l_r[4];
#pragma unroll
        for (int r = 0; r < 4; r++) { m_r[r] = -1e30f; l_r[r] = 0.f; }
        f32x4 accO[8];
#pragma unroll
        for (int nt = 0; nt < 8; nt++) accO[nt] = (f32x4){0.f, 0.f, 0.f, 0.f};

        const int nkt = qt + 1;   // 64-key tiles: keys 0 .. (qt+1)*64-1

        for (int kt = 0; kt < nkt; kt++) {
            const int kt0 = kt * 64;
            __syncthreads();   // protect Kt/Vt/Ps from previous readers
            // Stage K-tile: 64 rows x 192 bf16. Thread t: row t>>2, 48-col chunk.
            {
                const int kr = t >> 2;
                const int c0 = (t & 3) * 48;
                const short8* src = (const short8*)(Kc + ((size_t)(b * S_ + kt0 + kr) * NH + h) * 192 + c0);
                short8* dst = (short8*)&Kt[kr * 200 + c0];
#pragma unroll
                for (int c = 0; c < 6; c++) dst[c] = src[c];
            }
            // Stage V-tile transposed: coalesced 4xshort8 row read, scatter to LDS.
            {
                const int ki = t >> 2;
                const short8* vsrc = (const short8*)(Vb + ((size_t)(b * NH + h) * S_ + kt0 + ki) * 128);
                short8 vv[4];
#pragma unroll
                for (int c = 0; c < 4; c++) vv[c] = vsrc[(t & 3) * 4 + c];
#pragma unroll
                for (int c = 0; c < 4; c++)
#pragma unroll
                    for (int e = 0; e < 8; e++) {
                        const int dv = (t & 3) * 32 + c * 8 + e;
                        Vt[dv * 72 + ki] = (unsigned short)vv[c][e];
                    }
            }
            __syncthreads();

            // Scores: four 16-key n-tiles, K=192 in 6 mfma steps each.
            f32x4 s[4];
            __builtin_amdgcn_s_setprio(1);
#pragma unroll
            for (int nt = 0; nt < 4; nt++) {
                f32x4 acc = (f32x4){0.f, 0.f, 0.f, 0.f};
#pragma unroll
                for (int kc = 0; kc < 6; kc++) {
                    const short8 kf = *(const short8*)&Kt[(nt * 16 + col) * 200 + kc * 32 + quad * 8];
                    acc = __builtin_amdgcn_mfma_f32_16x16x32_bf16(qfrag[kc], kf, acc, 0, 0, 0);
                }
                s[nt] = acc;
            }
            __builtin_amdgcn_s_setprio(0);
            // Scale + causal mask
#pragma unroll
            for (int nt = 0; nt < 4; nt++)
#pragma unroll
                for (int r = 0; r < 4; r++) {
                    const int kg = kt0 + nt * 16 + col;
                    const int qg = q0 + wq * 16 + quad * 4 + r;
                    const float v = s[nt][r] * scale;
                    s[nt][r] = (kg > qg) ? -1e30f : v;
                }
            // Online softmax per query row
            float alpha[4];
#pragma unroll
            for (int r = 0; r < 4; r++) {
                float mt = fmaxf(fmaxf(s[0][r], s[1][r]), fmaxf(s[2][r], s[3][r]));
                mt = fmaxf(mt, __shfl_xor(mt, 1));
                mt = fmaxf(mt, __shfl_xor(mt, 2));
                mt = fmaxf(mt, __shfl_xor(mt, 4));
                mt = fmaxf(mt, __shfl_xor(mt, 8));
                const float mn = fmaxf(m_r[r], mt);
                alpha[r] = __expf(m_r[r] - mn);
                m_r[r] = mn;
                float rs = 0.f;
#pragma unroll
                for (int nt = 0; nt < 4; nt++) {
                    const float p = __expf(s[nt][r] - mn);
                    s[nt][r] = p;
                    rs += p;
                }
                rs += __shfl_xor(rs, 1);
                rs += __shfl_xor(rs, 2);
                rs += __shfl_xor(rs, 4);
                rs += __shfl_xor(rs, 8);
                l_r[r] = l_r[r] * alpha[r] + rs;
            }
            // P (C-layout) -> bf16 LDS -> reread in A-layout (per-wave region).
            {
                unsigned short* pw = &Ps[wq * 1152];
#pragma unroll
                for (int nt = 0; nt < 4; nt++)
#pragma unroll
                    for (int r = 0; r < 4; r++) {
                        bf16 hv = f2b(s[nt][r]);
                        pw[(quad * 4 + r) * 72 + nt * 16 + col] = *(unsigned short*)&hv;
                    }
            }
            short8 pf[2];
#pragma unroll
            for (int kk = 0; kk < 2; kk++)
                pf[kk] = *(const short8*)&Ps[wq * 1152 + col * 72 + kk * 32 + quad * 8];
            // Rescale O, then accumulate P.V (k = 64 in two 32-steps).
#pragma unroll
            for (int nt = 0; nt < 8; nt++)
#pragma unroll
                for (int r = 0; r < 4; r++) accO[nt][r] *= alpha[r];
            __builtin_amdgcn_s_setprio(1);
#pragma unroll
            for (int nt = 0; nt < 8; nt++) {
#pragma unroll
                for (int kk = 0; kk < 2; kk++) {
                    const short8 vf = *(const short8*)&Vt[(nt * 16 + col) * 72 + kk * 32 + quad * 8];
                    accO[nt] = __builtin_amdgcn_mfma_f32_16x16x32_bf16(pf[kk], vf, accO[nt], 0, 0, 0);
                }
            }
            __builtin_amdgcn_s_setprio(0);
        }

        // Epilogue for this tile
        float rinv[4];
#pragma unroll
        for (int r = 0; r < 4; r++) rinv[r] = 1.f / l_r[r];
#pragma unroll
        for (int nt = 0; nt < 8; nt++) {
            const int dv = nt * 16 + col;
            const float iov = io_s[dv];
#pragma unroll
            for (int r = 0; r < 4; r++) {
                const int q = q0 + wq * 16 + quad * 4 + r;
                O[((size_t)(b * S_ + q) * NH + h) * VD + dv] = f2b(accO[nt][r] * rinv[r] + iov);
            }
        }
    }
}

// ---------------------------------------------------------------------------
// Workspace lifetime plan (within proven ~100.8 MB):
//   rbig @0 (33.5MB): cq fp32 -> { ist fp32 [0,16M) ; kvn bf16 [16M,32M) }
//                      -> attnb bf16 [0,16M)
//   qp   @32MB (25.2MB)
//   kvc  @56MB (25.2MB): cq_bf16 (pre-kvc) -> kvc
//   Vb/Wt @80MB (16.8MB): Wt transposes -> Vb -> Wt(W_o)
//   gate @96MB (131KB): gate -> WkvT (64KB, post-sparse)
//   iob  @96MB+128KB
//   x_bf16 lives in d_out (dead before the final GEMM writes out).
// ---------------------------------------------------------------------------
extern "C" void kernel_launch(void* const* d_in, const int* in_sizes, int n_in,
                              void* d_out, int out_size, void* d_ws, size_t ws_size,
                              hipStream_t stream) {
    const float* x      = (const float*)d_in[0];
    const float* W_cq   = (const float*)d_in[1];
    const float* qn_w   = (const float*)d_in[2];
    const float* qn_b   = (const float*)d_in[3];
    const float* W_q    = (const float*)d_in[4];
    const float* W_ckv  = (const float*)d_in[5];
    const float* kvn_w  = (const float*)d_in[6];
    const float* kvn_b  = (const float*)d_in[7];
    const float* W_kv   = (const float*)d_in[8];
    const float* W_o    = (const float*)d_in[9];
    const float* W_ip   = (const float*)d_in[10];
    const float* W_ig   = (const float*)d_in[11];
    const float* W_sq   = (const float*)d_in[12];
    const float* W_sk   = (const float*)d_in[13];
    const float* W_sv   = (const float*)d_in[14];
    const float* W_io   = (const float*)d_in[15];
    float* out = (float*)d_out;

    const int M = B_ * S_;

    char* wsb = (char*)d_ws;
    float* rbig  = (float*)wsb;
    bf16*  kvn   = (bf16*)(wsb + 16777216);   // upper half of rbig
    bf16*  qp    = (bf16*)(wsb + 33554432);
    bf16*  kvc   = (bf16*)(wsb + 58720256);
    bf16*  cqb   = (bf16*)(wsb + 58720256);   // alias kvc (dead before kvc)
    bf16*  Vb    = (bf16*)(wsb + 83886080);
    bf16*  Wt    = (bf16*)(wsb + 83886080);   // alias Vb (disjoint lifetimes)
    float* gate  = (float*)(wsb + 100663296);
    bf16*  WkvT  = (bf16*)(wsb + 100663296);  // alias gate (post-sparse)
    float* iob   = (float*)(wsb + 100794368);
    float* cq    = rbig;
    float* ist   = rbig;
    bf16*  attnb = (bf16*)rbig;
    bf16*  xb    = (bf16*)d_out;              // x_bf16 in output buffer

    dim3 blk(256);

    // Stage 0: casts
    cast_bf16_k<<<dim3(2048), blk, 0, stream>>>(x, xb, M * H_ / 4);

    // qc = LN(x @ W_cq)
    transpose_cast_k<<<dim3(QLR / 32, H_ / 32), blk, 0, stream>>>(W_cq, Wt, H_, QLR);
    gemm_bt_mfma_k<float><<<dim3(QLR / 128, M / 128), blk, 0, stream>>>(xb, Wt, cq, M, QLR, H_);
    layernorm_cast_k<<<dim3(M), blk, 0, stream>>>(cq, qn_w, qn_b, cqb, QLR);

    // qp = qc @ W_q
    transpose_cast_k<<<dim3(3072 / 32, QLR / 32), blk, 0, stream>>>(W_q, Wt, QLR, 3072);
    gemm_bt_mfma_k<bf16><<<dim3(3072 / 128, M / 128), blk, 0, stream>>>(cqb, Wt, qp, M, 3072, QLR);

    // kvc = x @ W_ckv
    transpose_cast_k<<<dim3(3072 / 32, H_ / 32), blk, 0, stream>>>(W_ckv, Wt, H_, 3072);
    gemm_bt_mfma_k<bf16><<<dim3(3072 / 128, M / 128), blk, 0, stream>>>(xb, Wt, kvc, M, 3072, H_);

    // ist = x @ W_ip (fp32 out for sparse branch)
    transpose_cast_k<<<dim3(1024 / 32, H_ / 32), blk, 0, stream>>>(W_ip, Wt, H_, 1024);
    gemm_bt_mfma_k<float><<<dim3(1024 / 128, M / 128), blk, 0, stream>>>(xb, Wt, ist, M, IH * ID, H_);

    // gate = x @ W_ig — EXACT fp32 (top-k index stability)
    gemm_k<float, float, float><<<dim3(1, M / 64), blk, 0, stream>>>(x, W_ig, gate, M, IH, H_);

    q_rope_k<<<dim3(2048), blk, 0, stream>>>(qp);

    // KV path: LN+RoPE (wave-per-row) -> bf16 kvn; then MFMA matmul w/ scatter.
    kv_ln_k<<<dim3(B_ * S_ * NH / 4), blk, 0, stream>>>(kvc, kvn_w, kvn_b, kvn);

    sparse_k<<<dim3(B_ * IH), blk, 0, stream>>>(gate, ist, W_sq, W_sk, W_sv, W_io, iob);

    // Wkv^T (128x256 fp32 -> 256x128 bf16) into dead gate buffer
    transpose_cast_k<<<dim3(256 / 32, 128 / 32), blk, 0, stream>>>(W_kv, WkvT, 128, 256);
    gemm_kv_k<<<dim3(2, (B_ * S_ * NH) / 128), blk, 0, stream>>>(kvn, WkvT, kvc, Vb);

    // attention -> bf16 attn (rbig; ist/kvn already consumed)
    attn_mfma_k<<<dim3(16, NH, B_), blk, 0, stream>>>(qp, kvc, Vb, iob, attnb);

    // out = attn @ W_o (Vb dead -> reuse for W_o^T)
    transpose_cast_k<<<dim3(H_ / 32, H_ / 32), blk, 0, stream>>>(W_o, Wt, H_, H_);
    gemm_bt_mfma_k<float><<<dim3(H_ / 128, M / 128), blk, 0, stream>>>(attnb, Wt, out, M, H_, H_);
}

// Round 4
// 722.787 us; speedup vs baseline: 4.9798x; 1.1904x over previous
//
#include <hip/hip_runtime.h>
#include <hip/hip_bf16.h>
#include <math.h>

// Problem constants
#define NH    16
#define NOPE  128
#define ROPED 64
#define VD    128
#define QLR   1536
#define IH    8
#define ID    128
#define TOPK  8
#define EPSF  1e-5f
#define B_    2
#define S_    2048
#define H_    2048

using bf16 = __hip_bfloat16;
typedef __attribute__((ext_vector_type(8))) short short8;
typedef __attribute__((ext_vector_type(4))) short short4v;
typedef __attribute__((ext_vector_type(4))) float f32x4;

#define GLOBAL_AS __attribute__((address_space(1)))
#define LDS_AS    __attribute__((address_space(3)))

__device__ __forceinline__ float b2f(bf16 v) { return __bfloat162float(v); }
__device__ __forceinline__ bf16 f2b(float v) { return __float2bfloat16(v); }
__device__ __forceinline__ void stoC(float* p, float v) { *p = v; }
__device__ __forceinline__ void stoC(bf16* p, float v) { *p = __float2bfloat16(v); }

// ---------------------------------------------------------------------------
// NEW: dedicated gate projection: gate[M x 8] = x[M x H] @ W_ig[H x 8].
// Exact fp32. One wave per row; lane reads coalesced float4 of x; W_ig rows
// read contiguously per lane (128 B/lane/step, L2-resident). 8 fp32 accs,
// xor-shuffle reduce, lane 0 writes.
// ---------------------------------------------------------------------------
__global__ __launch_bounds__(256) void gate_k(const float* __restrict__ x,
                                              const float* __restrict__ Wg,
                                              float* __restrict__ gate) {
    const int t = threadIdx.x;
    const int wid = t >> 6, lane = t & 63;
    const int row = blockIdx.x * 4 + wid;
    const float* xp = x + (size_t)row * H_;

    float acc[8] = {};
    for (int k0 = 0; k0 < H_; k0 += 256) {
        const int kb = k0 + lane * 4;
        const f32x4 xv = *(const f32x4*)(xp + kb);
        const f32x4 w0 = *(const f32x4*)(Wg + (size_t)kb * 8);       // row kb,   cols 0-3
        const f32x4 w1 = *(const f32x4*)(Wg + (size_t)kb * 8 + 4);   //           cols 4-7
        const f32x4 w2 = *(const f32x4*)(Wg + (size_t)(kb + 1) * 8);
        const f32x4 w3 = *(const f32x4*)(Wg + (size_t)(kb + 1) * 8 + 4);
        const f32x4 w4 = *(const f32x4*)(Wg + (size_t)(kb + 2) * 8);
        const f32x4 w5 = *(const f32x4*)(Wg + (size_t)(kb + 2) * 8 + 4);
        const f32x4 w6 = *(const f32x4*)(Wg + (size_t)(kb + 3) * 8);
        const f32x4 w7 = *(const f32x4*)(Wg + (size_t)(kb + 3) * 8 + 4);
#pragma unroll
        for (int j = 0; j < 4; j++) {
            acc[j]     += xv[0] * w0[j] + xv[1] * w2[j] + xv[2] * w4[j] + xv[3] * w6[j];
            acc[4 + j] += xv[0] * w1[j] + xv[1] * w3[j] + xv[2] * w5[j] + xv[3] * w7[j];
        }
    }
#pragma unroll
    for (int j = 0; j < 8; j++) {
#pragma unroll
        for (int off = 32; off > 0; off >>= 1)
            acc[j] += __shfl_xor(acc[j], off);
    }
    if (lane == 0) {
#pragma unroll
        for (int j = 0; j < 8; j++) gate[(size_t)row * 8 + j] = acc[j];
    }
}

// ---------------------------------------------------------------------------
// bf16 MFMA GEMM, m97 structure (verified R1).
// C = A @ Bt^T, A MxK bf16 row-major, Bt NxK bf16 row-major.
// ---------------------------------------------------------------------------
template <typename OT>
__global__ __launch_bounds__(256) void gemm_bt_mfma_k(const bf16* __restrict__ A,
                                                      const bf16* __restrict__ Bt,
                                                      OT* __restrict__ C,
                                                      int M, int N, int K) {
    __shared__ bf16 As[128 * 32];
    __shared__ bf16 Bs[128 * 32];
    const int t = threadIdx.x;
    const int w = t >> 6;
    const int l = t & 63;
    const int col = l & 15;
    const int quad = l >> 4;
    const int wm = w >> 1, wn = w & 1;
    const int row0 = blockIdx.y * 128;
    const int col0 = blockIdx.x * 128;

    const int rA = l >> 2;
    const int cA = (l & 3) * 8;
    const bf16* ga0 = A + (size_t)(row0 + w * 16 + rA) * K + cA;
    const bf16* ga1 = A + (size_t)(row0 + (4 + w) * 16 + rA) * K + cA;
    const bf16* gb0 = Bt + (size_t)(col0 + w * 16 + rA) * K + cA;
    const bf16* gb1 = Bt + (size_t)(col0 + (4 + w) * 16 + rA) * K + cA;
    bf16* lA0 = &As[w * 512];
    bf16* lA1 = &As[(4 + w) * 512];
    bf16* lB0 = &Bs[w * 512];
    bf16* lB1 = &Bs[(4 + w) * 512];

    f32x4 acc[4][4];
#pragma unroll
    for (int i = 0; i < 4; i++)
#pragma unroll
        for (int j = 0; j < 4; j++) acc[i][j] = (f32x4){0.f, 0.f, 0.f, 0.f};

    for (int k0 = 0; k0 < K; k0 += 32) {
        __syncthreads();
        __builtin_amdgcn_global_load_lds((const GLOBAL_AS void*)(ga0 + k0),
                                         (LDS_AS void*)lA0, 16, 0, 0);
        __builtin_amdgcn_global_load_lds((const GLOBAL_AS void*)(ga1 + k0),
                                         (LDS_AS void*)lA1, 16, 0, 0);
        __builtin_amdgcn_global_load_lds((const GLOBAL_AS void*)(gb0 + k0),
                                         (LDS_AS void*)lB0, 16, 0, 0);
        __builtin_amdgcn_global_load_lds((const GLOBAL_AS void*)(gb1 + k0),
                                         (LDS_AS void*)lB1, 16, 0, 0);
        __syncthreads();

        short8 af[4], bfr[4];
#pragma unroll
        for (int i = 0; i < 4; i++) {
            af[i]  = *(const short8*)&As[(wm * 64 + i * 16 + col) * 32 + quad * 8];
            bfr[i] = *(const short8*)&Bs[(wn * 64 + i * 16 + col) * 32 + quad * 8];
        }
#pragma unroll
        for (int i = 0; i < 4; i++)
#pragma unroll
            for (int j = 0; j < 4; j++)
                acc[i][j] = __builtin_amdgcn_mfma_f32_16x16x32_bf16(af[i], bfr[j], acc[i][j], 0, 0, 0);
    }

#pragma unroll
    for (int i = 0; i < 4; i++)
#pragma unroll
        for (int j = 0; j < 4; j++)
#pragma unroll
            for (int r = 0; r < 4; r++) {
                const int gr = row0 + wm * 64 + i * 16 + quad * 4 + r;
                const int gc = col0 + wn * 64 + j * 16 + col;
                stoC(C + (size_t)gr * N + gc, acc[i][j][r]);
            }
}

// ---------------------------------------------------------------------------
// kv matmul on MFMA with scatter epilogue. A = kvn [65536 x 128] bf16,
// Bt = WkvT [256 x 128] bf16. Out col<128 -> kvc[row*192+col] (k_nope);
// col>=128 -> Vb. Row = ((b*S_+s)*NH)+h.
// ---------------------------------------------------------------------------
__global__ __launch_bounds__(256) void gemm_kv_k(const bf16* __restrict__ A,
                                                 const bf16* __restrict__ Bt,
                                                 bf16* __restrict__ kvc,
                                                 bf16* __restrict__ Vb) {
    __shared__ bf16 As[128 * 32];
    __shared__ bf16 Bs[128 * 32];
    const int K = 128;
    const int t = threadIdx.x;
    const int w = t >> 6;
    const int l = t & 63;
    const int col = l & 15;
    const int quad = l >> 4;
    const int wm = w >> 1, wn = w & 1;
    const int row0 = blockIdx.y * 128;
    const int col0 = blockIdx.x * 128;

    const int rA = l >> 2;
    const int cA = (l & 3) * 8;
    const bf16* ga0 = A + (size_t)(row0 + w * 16 + rA) * K + cA;
    const bf16* ga1 = A + (size_t)(row0 + (4 + w) * 16 + rA) * K + cA;
    const bf16* gb0 = Bt + (size_t)(col0 + w * 16 + rA) * K + cA;
    const bf16* gb1 = Bt + (size_t)(col0 + (4 + w) * 16 + rA) * K + cA;
    bf16* lA0 = &As[w * 512];
    bf16* lA1 = &As[(4 + w) * 512];
    bf16* lB0 = &Bs[w * 512];
    bf16* lB1 = &Bs[(4 + w) * 512];

    f32x4 acc[4][4];
#pragma unroll
    for (int i = 0; i < 4; i++)
#pragma unroll
        for (int j = 0; j < 4; j++) acc[i][j] = (f32x4){0.f, 0.f, 0.f, 0.f};

    for (int k0 = 0; k0 < K; k0 += 32) {
        __syncthreads();
        __builtin_amdgcn_global_load_lds((const GLOBAL_AS void*)(ga0 + k0),
                                         (LDS_AS void*)lA0, 16, 0, 0);
        __builtin_amdgcn_global_load_lds((const GLOBAL_AS void*)(ga1 + k0),
                                         (LDS_AS void*)lA1, 16, 0, 0);
        __builtin_amdgcn_global_load_lds((const GLOBAL_AS void*)(gb0 + k0),
                                         (LDS_AS void*)lB0, 16, 0, 0);
        __builtin_amdgcn_global_load_lds((const GLOBAL_AS void*)(gb1 + k0),
                                         (LDS_AS void*)lB1, 16, 0, 0);
        __syncthreads();

        short8 af[4], bfr[4];
#pragma unroll
        for (int i = 0; i < 4; i++) {
            af[i]  = *(const short8*)&As[(wm * 64 + i * 16 + col) * 32 + quad * 8];
            bfr[i] = *(const short8*)&Bs[(wn * 64 + i * 16 + col) * 32 + quad * 8];
        }
#pragma unroll
        for (int i = 0; i < 4; i++)
#pragma unroll
            for (int j = 0; j < 4; j++)
                acc[i][j] = __builtin_amdgcn_mfma_f32_16x16x32_bf16(af[i], bfr[j], acc[i][j], 0, 0, 0);
    }

#pragma unroll
    for (int i = 0; i < 4; i++)
#pragma unroll
        for (int j = 0; j < 4; j++)
#pragma unroll
            for (int r = 0; r < 4; r++) {
                const int gr = row0 + wm * 64 + i * 16 + quad * 4 + r;
                const int gc = col0 + wn * 64 + j * 16 + col;
                const int bb = gr >> 15;
                const int ss = (gr >> 4) & (S_ - 1);
                const int hh = gr & (NH - 1);
                const bf16 v = f2b(acc[i][j][r]);
                if (gc < 128) kvc[(size_t)gr * 192 + gc] = v;
                else Vb[(((size_t)(bb * NH + hh)) * S_ + ss) * 128 + (gc - 128)] = v;
            }
}

// ---------------------------------------------------------------------------
// Wave-per-row LN of kv_nope -> bf16 kvn, plus RoPE of k_pe written to
// kvc cols 128..191 (k_nope cols 0..127 filled later by gemm_kv_k).
// ---------------------------------------------------------------------------
__global__ __launch_bounds__(256) void kv_ln_k(bf16* __restrict__ kvc,
                                               const float* __restrict__ knw,
                                               const float* __restrict__ knb,
                                               bf16* __restrict__ kvn) {
    const int idx = blockIdx.x * 4 + (threadIdx.x >> 6);   // row 0..65535
    const int lane = threadIdx.x & 63;
    const int s = (idx >> 4) & (S_ - 1);
    const size_t base = (size_t)idx * 192;

    const float v0 = b2f(kvc[base + 64 + lane]);
    const float v1 = b2f(kvc[base + 128 + lane]);
    float xr = 0.f, xi = 0.f;
    if (lane < 32) { xr = b2f(kvc[base + 2 * lane]); xi = b2f(kvc[base + 2 * lane + 1]); }

    float s1 = v0 + v1, s2 = v0 * v0 + v1 * v1;
#pragma unroll
    for (int off = 32; off > 0; off >>= 1) {
        s1 += __shfl_xor(s1, off);
        s2 += __shfl_xor(s2, off);
    }
    const float mu = s1 * (1.f / 128.f);
    const float rinv = rsqrtf(s2 * (1.f / 128.f) - mu * mu + EPSF);
    kvn[(size_t)idx * 128 + lane]      = f2b((v0 - mu) * rinv * knw[lane] + knb[lane]);
    kvn[(size_t)idx * 128 + lane + 64] = f2b((v1 - mu) * rinv * knw[lane + 64] + knb[lane + 64]);

    if (lane < 32) {
        const float freq = powf(10000.f, -(float)(2 * lane) / 64.f);
        const float ang = (float)s * freq;
        float sn, c; sincosf(ang, &sn, &c);
        kvc[base + 128 + 2 * lane]     = f2b(xr * c - xi * sn);
        kvc[base + 128 + 2 * lane + 1] = f2b(xr * sn + xi * c);
    }
}

// ---------------------------------------------------------------------------
// Elementwise fp32 -> bf16 cast.
// ---------------------------------------------------------------------------
__global__ __launch_bounds__(256) void cast_bf16_k(const float* __restrict__ X,
                                                   bf16* __restrict__ Y, int n4) {
    for (int i = blockIdx.x * 256 + threadIdx.x; i < n4; i += gridDim.x * 256) {
        const f32x4 v = ((const f32x4*)X)[i];
        short4v o;
#pragma unroll
        for (int j = 0; j < 4; j++) {
            bf16 b = f2b(v[j]);
            o[j] = *(short*)&b;
        }
        ((short4v*)Y)[i] = o;
    }
}

// ---------------------------------------------------------------------------
// Tiled transpose-cast: W (KxN fp32) -> Wt (NxK bf16).
// ---------------------------------------------------------------------------
__global__ __launch_bounds__(256) void transpose_cast_k(const float* __restrict__ W,
                                                        bf16* __restrict__ Wt,
                                                        int K, int N) {
    __shared__ float tile[32][33];
    const int t = threadIdx.x;
    const int tx = t & 31, ty = t >> 5;
    const int n0 = blockIdx.x * 32;
    const int k0 = blockIdx.y * 32;
#pragma unroll
    for (int i = 0; i < 4; i++)
        tile[ty + 8 * i][tx] = W[(size_t)(k0 + ty + 8 * i) * N + n0 + tx];
    __syncthreads();
#pragma unroll
    for (int i = 0; i < 4; i++)
        Wt[(size_t)(n0 + ty + 8 * i) * K + k0 + tx] = f2b(tile[tx][ty + 8 * i]);
}

// ---------------------------------------------------------------------------
// Row layernorm emitting bf16.
// ---------------------------------------------------------------------------
__global__ __launch_bounds__(256) void layernorm_cast_k(const float* __restrict__ X,
                                                        const float* __restrict__ w,
                                                        const float* __restrict__ b,
                                                        bf16* __restrict__ Y,
                                                        int L) {
    __shared__ float r1[256], r2[256];
    const int row = blockIdx.x;
    const int t = threadIdx.x;
    const float* xp = X + (size_t)row * L;
    bf16* yp = Y + (size_t)row * L;
    float s1 = 0.f, s2 = 0.f;
    for (int j = t; j < L; j += 256) { const float v = xp[j]; s1 += v; s2 += v * v; }
    r1[t] = s1; r2[t] = s2; __syncthreads();
    for (int off = 128; off > 0; off >>= 1) {
        if (t < off) { r1[t] += r1[t + off]; r2[t] += r2[t + off]; }
        __syncthreads();
    }
    const float mu   = r1[0] / (float)L;
    const float var  = r2[0] / (float)L - mu * mu;
    const float rinv = rsqrtf(var + EPSF);
    for (int j = t; j < L; j += 256)
        yp[j] = f2b((xp[j] - mu) * rinv * w[j] + b[j]);
}

// ---------------------------------------------------------------------------
// In-place RoPE on qp.
// ---------------------------------------------------------------------------
__global__ __launch_bounds__(256) void q_rope_k(bf16* __restrict__ qp) {
    const int total = B_ * S_ * NH * 32;
    for (int p = blockIdx.x * 256 + threadIdx.x; p < total; p += gridDim.x * 256) {
        const int j = p & 31;
        const int row = p >> 5;
        const int sr = row >> 4;
        const int s = sr & (S_ - 1);
        const size_t base = (size_t)row * 192 + 128 + 2 * j;
        const float xr = b2f(qp[base]);
        const float xi = b2f(qp[base + 1]);
        const float freq = powf(10000.f, -(float)(2 * j) / 64.f);
        const float ang = (float)s * freq;
        float sn, c; sincosf(ang, &sn, &c);
        qp[base]     = f2b(xr * c - xi * sn);
        qp[base + 1] = f2b(xr * sn + xi * c);
    }
}

// ---------------------------------------------------------------------------
// Sparse branch (unchanged).
// ---------------------------------------------------------------------------
__global__ __launch_bounds__(256) void sparse_k(const float* __restrict__ gate,
                                                const float* __restrict__ ist,
                                                const float* __restrict__ Wsq,
                                                const float* __restrict__ Wsk,
                                                const float* __restrict__ Wsv,
                                                const float* __restrict__ Wio,
                                                float* __restrict__ io) {
    __shared__ float g[S_];
    __shared__ float sel[TOPK][ID];
    __shared__ float sq[TOPK][ID], sk[TOPK][ID], sv[TOPK][ID];
    __shared__ float sp[TOPK][TOPK];
    __shared__ float ms[ID];
    __shared__ float rv[256];
    __shared__ int ri[256];
    __shared__ int sidx[TOPK];
    const int bi = blockIdx.x;
    const int ih = bi % IH;
    const int b = bi / IH;
    const int t = threadIdx.x;

    for (int s = t; s < S_; s += 256) g[s] = gate[(size_t)(b * S_ + s) * IH + ih];
    __syncthreads();

    for (int r = 0; r < TOPK; r++) {
        float bv = -INFINITY; int bx = S_;
        for (int s = t; s < S_; s += 256) {
            const float v = g[s];
            if (v > bv) { bv = v; bx = s; }
        }
        rv[t] = bv; ri[t] = bx; __syncthreads();
        for (int off = 128; off > 0; off >>= 1) {
            if (t < off) {
                const float v2 = rv[t + off]; const int i2 = ri[t + off];
                if (v2 > rv[t] || (v2 == rv[t] && i2 < ri[t])) { rv[t] = v2; ri[t] = i2; }
            }
            __syncthreads();
        }
        if (t == 0) { sidx[r] = ri[0]; g[ri[0]] = -INFINITY; }
        __syncthreads();
    }

    for (int i = t; i < TOPK * ID; i += 256) {
        const int r = i >> 7, d = i & 127;
        sel[r][d] = ist[((size_t)(b * S_ + sidx[r]) * IH + ih) * ID + d];
    }
    __syncthreads();

    for (int i = t; i < TOPK * ID; i += 256) {
        const int r = i >> 7, n = i & 127;
        float aq = 0.f, ak = 0.f, av = 0.f;
        for (int k = 0; k < 128; k++) {
            const float s = sel[r][k];
            aq += s * Wsq[k * ID + n];
            ak += s * Wsk[k * ID + n];
            av += s * Wsv[k * ID + n];
        }
        sq[r][n] = aq; sk[r][n] = ak; sv[r][n] = av;
    }
    __syncthreads();

    if (t < TOPK * TOPK) {
        const int r = t >> 3, c = t & 7;
        float a = 0.f;
        for (int k = 0; k < 128; k++) a += sq[r][k] * sk[c][k];
        sp[r][c] = a * 0.08838834764831845f;
    }
    __syncthreads();

    if (t < TOPK) {
        float m = -INFINITY;
        for (int c = 0; c < 8; c++) m = fmaxf(m, sp[t][c]);
        float e[8]; float sum = 0.f;
        for (int c = 0; c < 8; c++) { e[c] = expf(sp[t][c] - m); sum += e[c]; }
        for (int c = 0; c < 8; c++) sp[t][c] = e[c] / sum;
    }
    __syncthreads();

    if (t < ID) {
        float acc = 0.f;
        for (int r = 0; r < 8; r++) {
            float so = 0.f;
            for (int c = 0; c < 8; c++) so += sp[r][c] * sv[c][t];
            acc += so;
        }
        ms[t] = acc * 0.125f;
    }
    __syncthreads();

    if (t < ID) {
        float acc = 0.f;
        for (int k = 0; k < 128; k++) acc += ms[k] * Wio[(size_t)k * H_ + t];
        io[((size_t)b * IH + ih) * ID + t] = acc;
    }
}

// ---------------------------------------------------------------------------
// MFMA flash attention v2 (verified R3): q-tile pairs (i, 31-i), KVBLK=64,
// setprio, bijective XCD swizzle. Grid (16, NH, B_) = 512 blocks.
// ---------------------------------------------------------------------------
__global__ __launch_bounds__(256) void attn_mfma_k(const bf16* __restrict__ Qp,
                                                   const bf16* __restrict__ Kc,
                                                   const bf16* __restrict__ Vb,
                                                   const float* __restrict__ io,
                                                   bf16* __restrict__ O) {
    __shared__ unsigned short Kt[64 * 200];    // 64 keys x 192 dims (+8 pad)
    __shared__ unsigned short Vt[128 * 72];    // V^T: 128 dv x 64 keys (+8 pad)
    __shared__ unsigned short Ps[4 * 16 * 72]; // per-wave P patch 16q x 64k (+8)
    __shared__ float io_s[128];

    // Chunked XCD swizzle (bijective: 512 = 8 * 64)
    const int lin = blockIdx.x + 16 * blockIdx.y + 256 * blockIdx.z;
    const int swz = (lin & 7) * 64 + (lin >> 3);
    const int pairi = swz & 15;
    const int h = (swz >> 4) & 15;
    const int b = swz >> 8;

    const int t = threadIdx.x;
    const int lane = t & 63;
    const int wq = t >> 6;
    const int col = lane & 15;
    const int quad = lane >> 4;

    if (t < 128) io_s[t] = io[((size_t)b * IH + (h >> 1)) * ID + t];

    const float scale = 0.07216878364870322f;  // 1/sqrt(192)

#pragma unroll 1
    for (int ti = 0; ti < 2; ti++) {
        const int qt = (ti == 0) ? pairi : 31 - pairi;
        const int q0 = qt * 64;

        // Q fragments for this tile
        short8 qfrag[6];
        {
            const int q = q0 + wq * 16 + col;
            const short8* qrow = (const short8*)(Qp + ((size_t)(b * S_ + q) * NH + h) * 192);
#pragma unroll
            for (int kc = 0; kc < 6; kc++) qfrag[kc] = qrow[kc * 4 + quad];
        }

        float m_r[4], l_r[4];
#pragma unroll
        for (int r = 0; r < 4; r++) { m_r[r] = -1e30f; l_r[r] = 0.f; }
        f32x4 accO[8];
#pragma unroll
        for (int nt = 0; nt < 8; nt++) accO[nt] = (f32x4){0.f, 0.f, 0.f, 0.f};

        const int nkt = qt + 1;   // 64-key tiles: keys 0 .. (qt+1)*64-1

        for (int kt = 0; kt < nkt; kt++) {
            const int kt0 = kt * 64;
            __syncthreads();   // protect Kt/Vt/Ps from previous readers
            // Stage K-tile: 64 rows x 192 bf16. Thread t: row t>>2, 48-col chunk.
            {
                const int kr = t >> 2;
                const int c0 = (t & 3) * 48;
                const short8* src = (const short8*)(Kc + ((size_t)(b * S_ + kt0 + kr) * NH + h) * 192 + c0);
                short8* dst = (short8*)&Kt[kr * 200 + c0];
#pragma unroll
                for (int c = 0; c < 6; c++) dst[c] = src[c];
            }
            // Stage V-tile transposed: coalesced 4xshort8 row read, scatter to LDS.
            {
                const int ki = t >> 2;
                const short8* vsrc = (const short8*)(Vb + ((size_t)(b * NH + h) * S_ + kt0 + ki) * 128);
                short8 vv[4];
#pragma unroll
                for (int c = 0; c < 4; c++) vv[c] = vsrc[(t & 3) * 4 + c];
#pragma unroll
                for (int c = 0; c < 4; c++)
#pragma unroll
                    for (int e = 0; e < 8; e++) {
                        const int dv = (t & 3) * 32 + c * 8 + e;
                        Vt[dv * 72 + ki] = (unsigned short)vv[c][e];
                    }
            }
            __syncthreads();

            // Scores: four 16-key n-tiles, K=192 in 6 mfma steps each.
            f32x4 s[4];
            __builtin_amdgcn_s_setprio(1);
#pragma unroll
            for (int nt = 0; nt < 4; nt++) {
                f32x4 acc = (f32x4){0.f, 0.f, 0.f, 0.f};
#pragma unroll
                for (int kc = 0; kc < 6; kc++) {
                    const short8 kf = *(const short8*)&Kt[(nt * 16 + col) * 200 + kc * 32 + quad * 8];
                    acc = __builtin_amdgcn_mfma_f32_16x16x32_bf16(qfrag[kc], kf, acc, 0, 0, 0);
                }
                s[nt] = acc;
            }
            __builtin_amdgcn_s_setprio(0);
            // Scale + causal mask
#pragma unroll
            for (int nt = 0; nt < 4; nt++)
#pragma unroll
                for (int r = 0; r < 4; r++) {
                    const int kg = kt0 + nt * 16 + col;
                    const int qg = q0 + wq * 16 + quad * 4 + r;
                    const float v = s[nt][r] * scale;
                    s[nt][r] = (kg > qg) ? -1e30f : v;
                }
            // Online softmax per query row
            float alpha[4];
#pragma unroll
            for (int r = 0; r < 4; r++) {
                float mt = fmaxf(fmaxf(s[0][r], s[1][r]), fmaxf(s[2][r], s[3][r]));
                mt = fmaxf(mt, __shfl_xor(mt, 1));
                mt = fmaxf(mt, __shfl_xor(mt, 2));
                mt = fmaxf(mt, __shfl_xor(mt, 4));
                mt = fmaxf(mt, __shfl_xor(mt, 8));
                const float mn = fmaxf(m_r[r], mt);
                alpha[r] = __expf(m_r[r] - mn);
                m_r[r] = mn;
                float rs = 0.f;
#pragma unroll
                for (int nt = 0; nt < 4; nt++) {
                    const float p = __expf(s[nt][r] - mn);
                    s[nt][r] = p;
                    rs += p;
                }
                rs += __shfl_xor(rs, 1);
                rs += __shfl_xor(rs, 2);
                rs += __shfl_xor(rs, 4);
                rs += __shfl_xor(rs, 8);
                l_r[r] = l_r[r] * alpha[r] + rs;
            }
            // P (C-layout) -> bf16 LDS -> reread in A-layout (per-wave region).
            {
                unsigned short* pw = &Ps[wq * 1152];
#pragma unroll
                for (int nt = 0; nt < 4; nt++)
#pragma unroll
                    for (int r = 0; r < 4; r++) {
                        bf16 hv = f2b(s[nt][r]);
                        pw[(quad * 4 + r) * 72 + nt * 16 + col] = *(unsigned short*)&hv;
                    }
            }
            short8 pf[2];
#pragma unroll
            for (int kk = 0; kk < 2; kk++)
                pf[kk] = *(const short8*)&Ps[wq * 1152 + col * 72 + kk * 32 + quad * 8];
            // Rescale O, then accumulate P.V (k = 64 in two 32-steps).
#pragma unroll
            for (int nt = 0; nt < 8; nt++)
#pragma unroll
                for (int r = 0; r < 4; r++) accO[nt][r] *= alpha[r];
            __builtin_amdgcn_s_setprio(1);
#pragma unroll
            for (int nt = 0; nt < 8; nt++) {
#pragma unroll
                for (int kk = 0; kk < 2; kk++) {
                    const short8 vf = *(const short8*)&Vt[(nt * 16 + col) * 72 + kk * 32 + quad * 8];
                    accO[nt] = __builtin_amdgcn_mfma_f32_16x16x32_bf16(pf[kk], vf, accO[nt], 0, 0, 0);
                }
            }
            __builtin_amdgcn_s_setprio(0);
        }

        // Epilogue for this tile
        float rinv[4];
#pragma unroll
        for (int r = 0; r < 4; r++) rinv[r] = 1.f / l_r[r];
#pragma unroll
        for (int nt = 0; nt < 8; nt++) {
            const int dv = nt * 16 + col;
            const float iov = io_s[dv];
#pragma unroll
            for (int r = 0; r < 4; r++) {
                const int q = q0 + wq * 16 + quad * 4 + r;
                O[((size_t)(b * S_ + q) * NH + h) * VD + dv] = f2b(accO[nt][r] * rinv[r] + iov);
            }
        }
    }
}

// ---------------------------------------------------------------------------
// Workspace lifetime plan (within proven ~100.8 MB):
//   rbig @0 (33.5MB): cq fp32 -> { ist fp32 [0,16M) ; kvn bf16 [16M,32M) }
//                      -> attnb bf16 [0,16M)
//   qp   @32MB (25.2MB)
//   kvc  @56MB (25.2MB): cq_bf16 (pre-kvc) -> kvc
//   Vb/Wt @80MB (16.8MB): Wt transposes -> Vb -> Wt(W_o)
//   gate @96MB (131KB): gate -> WkvT (64KB, post-sparse)
//   iob  @96MB+128KB
//   x_bf16 lives in d_out (dead before the final GEMM writes out).
// ---------------------------------------------------------------------------
extern "C" void kernel_launch(void* const* d_in, const int* in_sizes, int n_in,
                              void* d_out, int out_size, void* d_ws, size_t ws_size,
                              hipStream_t stream) {
    const float* x      = (const float*)d_in[0];
    const float* W_cq   = (const float*)d_in[1];
    const float* qn_w   = (const float*)d_in[2];
    const float* qn_b   = (const float*)d_in[3];
    const float* W_q    = (const float*)d_in[4];
    const float* W_ckv  = (const float*)d_in[5];
    const float* kvn_w  = (const float*)d_in[6];
    const float* kvn_b  = (const float*)d_in[7];
    const float* W_kv   = (const float*)d_in[8];
    const float* W_o    = (const float*)d_in[9];
    const float* W_ip   = (const float*)d_in[10];
    const float* W_ig   = (const float*)d_in[11];
    const float* W_sq   = (const float*)d_in[12];
    const float* W_sk   = (const float*)d_in[13];
    const float* W_sv   = (const float*)d_in[14];
    const float* W_io   = (const float*)d_in[15];
    float* out = (float*)d_out;

    const int M = B_ * S_;

    char* wsb = (char*)d_ws;
    float* rbig  = (float*)wsb;
    bf16*  kvn   = (bf16*)(wsb + 16777216);   // upper half of rbig
    bf16*  qp    = (bf16*)(wsb + 33554432);
    bf16*  kvc   = (bf16*)(wsb + 58720256);
    bf16*  cqb   = (bf16*)(wsb + 58720256);   // alias kvc (dead before kvc)
    bf16*  Vb    = (bf16*)(wsb + 83886080);
    bf16*  Wt    = (bf16*)(wsb + 83886080);   // alias Vb (disjoint lifetimes)
    float* gate  = (float*)(wsb + 100663296);
    bf16*  WkvT  = (bf16*)(wsb + 100663296);  // alias gate (post-sparse)
    float* iob   = (float*)(wsb + 100794368);
    float* cq    = rbig;
    float* ist   = rbig;
    bf16*  attnb = (bf16*)rbig;
    bf16*  xb    = (bf16*)d_out;              // x_bf16 in output buffer

    dim3 blk(256);

    // Stage 0: casts
    cast_bf16_k<<<dim3(2048), blk, 0, stream>>>(x, xb, M * H_ / 4);

    // qc = LN(x @ W_cq)
    transpose_cast_k<<<dim3(QLR / 32, H_ / 32), blk, 0, stream>>>(W_cq, Wt, H_, QLR);
    gemm_bt_mfma_k<float><<<dim3(QLR / 128, M / 128), blk, 0, stream>>>(xb, Wt, cq, M, QLR, H_);
    layernorm_cast_k<<<dim3(M), blk, 0, stream>>>(cq, qn_w, qn_b, cqb, QLR);

    // qp = qc @ W_q
    transpose_cast_k<<<dim3(3072 / 32, QLR / 32), blk, 0, stream>>>(W_q, Wt, QLR, 3072);
    gemm_bt_mfma_k<bf16><<<dim3(3072 / 128, M / 128), blk, 0, stream>>>(cqb, Wt, qp, M, 3072, QLR);

    // kvc = x @ W_ckv
    transpose_cast_k<<<dim3(3072 / 32, H_ / 32), blk, 0, stream>>>(W_ckv, Wt, H_, 3072);
    gemm_bt_mfma_k<bf16><<<dim3(3072 / 128, M / 128), blk, 0, stream>>>(xb, Wt, kvc, M, 3072, H_);

    // ist = x @ W_ip (fp32 out for sparse branch)
    transpose_cast_k<<<dim3(1024 / 32, H_ / 32), blk, 0, stream>>>(W_ip, Wt, H_, 1024);
    gemm_bt_mfma_k<float><<<dim3(1024 / 128, M / 128), blk, 0, stream>>>(xb, Wt, ist, M, IH * ID, H_);

    // gate = x @ W_ig — EXACT fp32 (top-k index stability), dedicated kernel
    gate_k<<<dim3(M / 4), blk, 0, stream>>>(x, W_ig, gate);

    q_rope_k<<<dim3(2048), blk, 0, stream>>>(qp);

    // KV path: LN+RoPE (wave-per-row) -> bf16 kvn; then MFMA matmul w/ scatter.
    kv_ln_k<<<dim3(B_ * S_ * NH / 4), blk, 0, stream>>>(kvc, kvn_w, kvn_b, kvn);

    sparse_k<<<dim3(B_ * IH), blk, 0, stream>>>(gate, ist, W_sq, W_sk, W_sv, W_io, iob);

    // Wkv^T (128x256 fp32 -> 256x128 bf16) into dead gate buffer
    transpose_cast_k<<<dim3(256 / 32, 128 / 32), blk, 0, stream>>>(W_kv, WkvT, 128, 256);
    gemm_kv_k<<<dim3(2, (B_ * S_ * NH) / 128), blk, 0, stream>>>(kvn, WkvT, kvc, Vb);

    // attention -> bf16 attn (rbig; ist/kvn already consumed)
    attn_mfma_k<<<dim3(16, NH, B_), blk, 0, stream>>>(qp, kvc, Vb, iob, attnb);

    // out = attn @ W_o (Vb dead -> reuse for W_o^T)
    transpose_cast_k<<<dim3(H_ / 32, H_ / 32), blk, 0, stream>>>(W_o, Wt, H_, H_);
    gemm_bt_mfma_k<float><<<dim3(H_ / 128, M / 128), blk, 0, stream>>>(attnb, Wt, out, M, H_, H_);
}

// Round 5
// 685.115 us; speedup vs baseline: 5.2536x; 1.0550x over previous
//
#include <hip/hip_runtime.h>
#include <hip/hip_bf16.h>
#include <math.h>

// Problem constants
#define NH    16
#define NOPE  128
#define ROPED 64
#define VD    128
#define QLR   1536
#define IH    8
#define ID    128
#define TOPK  8
#define EPSF  1e-5f
#define B_    2
#define S_    2048
#define H_    2048

using bf16 = __hip_bfloat16;
typedef __attribute__((ext_vector_type(8))) short short8;
typedef __attribute__((ext_vector_type(4))) short short4v;
typedef __attribute__((ext_vector_type(4))) float f32x4;

#define GLOBAL_AS __attribute__((address_space(1)))
#define LDS_AS    __attribute__((address_space(3)))

__device__ __forceinline__ float b2f(bf16 v) { return __bfloat162float(v); }
__device__ __forceinline__ bf16 f2b(float v) { return __float2bfloat16(v); }
__device__ __forceinline__ void stoC(float* p, float v) { *p = v; }
__device__ __forceinline__ void stoC(bf16* p, float v) { *p = __float2bfloat16(v); }

// ---------------------------------------------------------------------------
// Dedicated gate projection (exact fp32, verified R4).
// ---------------------------------------------------------------------------
__global__ __launch_bounds__(256) void gate_k(const float* __restrict__ x,
                                              const float* __restrict__ Wg,
                                              float* __restrict__ gate) {
    const int t = threadIdx.x;
    const int wid = t >> 6, lane = t & 63;
    const int row = blockIdx.x * 4 + wid;
    const float* xp = x + (size_t)row * H_;

    float acc[8] = {};
    for (int k0 = 0; k0 < H_; k0 += 256) {
        const int kb = k0 + lane * 4;
        const f32x4 xv = *(const f32x4*)(xp + kb);
        const f32x4 w0 = *(const f32x4*)(Wg + (size_t)kb * 8);
        const f32x4 w1 = *(const f32x4*)(Wg + (size_t)kb * 8 + 4);
        const f32x4 w2 = *(const f32x4*)(Wg + (size_t)(kb + 1) * 8);
        const f32x4 w3 = *(const f32x4*)(Wg + (size_t)(kb + 1) * 8 + 4);
        const f32x4 w4 = *(const f32x4*)(Wg + (size_t)(kb + 2) * 8);
        const f32x4 w5 = *(const f32x4*)(Wg + (size_t)(kb + 2) * 8 + 4);
        const f32x4 w6 = *(const f32x4*)(Wg + (size_t)(kb + 3) * 8);
        const f32x4 w7 = *(const f32x4*)(Wg + (size_t)(kb + 3) * 8 + 4);
#pragma unroll
        for (int j = 0; j < 4; j++) {
            acc[j]     += xv[0] * w0[j] + xv[1] * w2[j] + xv[2] * w4[j] + xv[3] * w6[j];
            acc[4 + j] += xv[0] * w1[j] + xv[1] * w3[j] + xv[2] * w5[j] + xv[3] * w7[j];
        }
    }
#pragma unroll
    for (int j = 0; j < 8; j++) {
#pragma unroll
        for (int off = 32; off > 0; off >>= 1)
            acc[j] += __shfl_xor(acc[j], off);
    }
    if (lane == 0) {
#pragma unroll
        for (int j = 0; j < 8; j++) gate[(size_t)row * 8 + j] = acc[j];
    }
}

// ---------------------------------------------------------------------------
// bf16 MFMA GEMM, m97 structure + bijective chunked XCD swizzle (T1).
// All call-site grids are multiples of 8 blocks.
// ---------------------------------------------------------------------------
template <typename OT>
__global__ __launch_bounds__(256) void gemm_bt_mfma_k(const bf16* __restrict__ A,
                                                      const bf16* __restrict__ Bt,
                                                      OT* __restrict__ C,
                                                      int M, int N, int K) {
    __shared__ bf16 As[128 * 32];
    __shared__ bf16 Bs[128 * 32];
    const int t = threadIdx.x;
    const int w = t >> 6;
    const int l = t & 63;
    const int col = l & 15;
    const int quad = l >> 4;
    const int wm = w >> 1, wn = w & 1;

    // XCD chunked swizzle: dispatch-linear -> work-linear (nwg % 8 == 0)
    const int gx = gridDim.x;
    const int nwg = gx * gridDim.y;
    const int lin = blockIdx.y * gx + blockIdx.x;
    const int work = (lin & 7) * (nwg >> 3) + (lin >> 3);
    const int row0 = (work / gx) * 128;
    const int col0 = (work % gx) * 128;

    const int rA = l >> 2;
    const int cA = (l & 3) * 8;
    const bf16* ga0 = A + (size_t)(row0 + w * 16 + rA) * K + cA;
    const bf16* ga1 = A + (size_t)(row0 + (4 + w) * 16 + rA) * K + cA;
    const bf16* gb0 = Bt + (size_t)(col0 + w * 16 + rA) * K + cA;
    const bf16* gb1 = Bt + (size_t)(col0 + (4 + w) * 16 + rA) * K + cA;
    bf16* lA0 = &As[w * 512];
    bf16* lA1 = &As[(4 + w) * 512];
    bf16* lB0 = &Bs[w * 512];
    bf16* lB1 = &Bs[(4 + w) * 512];

    f32x4 acc[4][4];
#pragma unroll
    for (int i = 0; i < 4; i++)
#pragma unroll
        for (int j = 0; j < 4; j++) acc[i][j] = (f32x4){0.f, 0.f, 0.f, 0.f};

    for (int k0 = 0; k0 < K; k0 += 32) {
        __syncthreads();
        __builtin_amdgcn_global_load_lds((const GLOBAL_AS void*)(ga0 + k0),
                                         (LDS_AS void*)lA0, 16, 0, 0);
        __builtin_amdgcn_global_load_lds((const GLOBAL_AS void*)(ga1 + k0),
                                         (LDS_AS void*)lA1, 16, 0, 0);
        __builtin_amdgcn_global_load_lds((const GLOBAL_AS void*)(gb0 + k0),
                                         (LDS_AS void*)lB0, 16, 0, 0);
        __builtin_amdgcn_global_load_lds((const GLOBAL_AS void*)(gb1 + k0),
                                         (LDS_AS void*)lB1, 16, 0, 0);
        __syncthreads();

        short8 af[4], bfr[4];
#pragma unroll
        for (int i = 0; i < 4; i++) {
            af[i]  = *(const short8*)&As[(wm * 64 + i * 16 + col) * 32 + quad * 8];
            bfr[i] = *(const short8*)&Bs[(wn * 64 + i * 16 + col) * 32 + quad * 8];
        }
#pragma unroll
        for (int i = 0; i < 4; i++)
#pragma unroll
            for (int j = 0; j < 4; j++)
                acc[i][j] = __builtin_amdgcn_mfma_f32_16x16x32_bf16(af[i], bfr[j], acc[i][j], 0, 0, 0);
    }

#pragma unroll
    for (int i = 0; i < 4; i++)
#pragma unroll
        for (int j = 0; j < 4; j++)
#pragma unroll
            for (int r = 0; r < 4; r++) {
                const int gr = row0 + wm * 64 + i * 16 + quad * 4 + r;
                const int gc = col0 + wn * 64 + j * 16 + col;
                stoC(C + (size_t)gr * N + gc, acc[i][j][r]);
            }
}

// ---------------------------------------------------------------------------
// kv matmul on MFMA. A = kvn [65536 x 128] bf16, Bt = WkvT [256 x 128] bf16.
// col-block 0 -> kvc[row*192 + gc] (k_nope, scalar scatter).
// col-block 1 -> VbT[(bh*128 + dv)*S_ + ss] -- TRANSPOSED V layout, written
//   as packed 8B stores (the 4 i-fragments are 4 consecutive ss).
// ---------------------------------------------------------------------------
__global__ __launch_bounds__(256) void gemm_kv_k(const bf16* __restrict__ A,
                                                 const bf16* __restrict__ Bt,
                                                 bf16* __restrict__ kvc,
                                                 bf16* __restrict__ VbT) {
    __shared__ bf16 As[128 * 32];
    __shared__ bf16 Bs[128 * 32];
    const int K = 128;
    const int t = threadIdx.x;
    const int w = t >> 6;
    const int l = t & 63;
    const int col = l & 15;
    const int quad = l >> 4;
    const int wm = w >> 1, wn = w & 1;

    const int gx = gridDim.x;
    const int nwg = gx * gridDim.y;
    const int lin = blockIdx.y * gx + blockIdx.x;
    const int work = (lin & 7) * (nwg >> 3) + (lin >> 3);
    const int row0 = (work / gx) * 128;
    const int col0 = (work % gx) * 128;

    const int rA = l >> 2;
    const int cA = (l & 3) * 8;
    const bf16* ga0 = A + (size_t)(row0 + w * 16 + rA) * K + cA;
    const bf16* ga1 = A + (size_t)(row0 + (4 + w) * 16 + rA) * K + cA;
    const bf16* gb0 = Bt + (size_t)(col0 + w * 16 + rA) * K + cA;
    const bf16* gb1 = Bt + (size_t)(col0 + (4 + w) * 16 + rA) * K + cA;
    bf16* lA0 = &As[w * 512];
    bf16* lA1 = &As[(4 + w) * 512];
    bf16* lB0 = &Bs[w * 512];
    bf16* lB1 = &Bs[(4 + w) * 512];

    f32x4 acc[4][4];
#pragma unroll
    for (int i = 0; i < 4; i++)
#pragma unroll
        for (int j = 0; j < 4; j++) acc[i][j] = (f32x4){0.f, 0.f, 0.f, 0.f};

    for (int k0 = 0; k0 < K; k0 += 32) {
        __syncthreads();
        __builtin_amdgcn_global_load_lds((const GLOBAL_AS void*)(ga0 + k0),
                                         (LDS_AS void*)lA0, 16, 0, 0);
        __builtin_amdgcn_global_load_lds((const GLOBAL_AS void*)(ga1 + k0),
                                         (LDS_AS void*)lA1, 16, 0, 0);
        __builtin_amdgcn_global_load_lds((const GLOBAL_AS void*)(gb0 + k0),
                                         (LDS_AS void*)lB0, 16, 0, 0);
        __builtin_amdgcn_global_load_lds((const GLOBAL_AS void*)(gb1 + k0),
                                         (LDS_AS void*)lB1, 16, 0, 0);
        __syncthreads();

        short8 af[4], bfr[4];
#pragma unroll
        for (int i = 0; i < 4; i++) {
            af[i]  = *(const short8*)&As[(wm * 64 + i * 16 + col) * 32 + quad * 8];
            bfr[i] = *(const short8*)&Bs[(wn * 64 + i * 16 + col) * 32 + quad * 8];
        }
#pragma unroll
        for (int i = 0; i < 4; i++)
#pragma unroll
            for (int j = 0; j < 4; j++)
                acc[i][j] = __builtin_amdgcn_mfma_f32_16x16x32_bf16(af[i], bfr[j], acc[i][j], 0, 0, 0);
    }

    if (col0 == 0) {
        // k_nope half -> kvc rows (stride 192)
#pragma unroll
        for (int i = 0; i < 4; i++)
#pragma unroll
            for (int j = 0; j < 4; j++)
#pragma unroll
                for (int r = 0; r < 4; r++) {
                    const int gr = row0 + wm * 64 + i * 16 + quad * 4 + r;
                    const int gc = wn * 64 + j * 16 + col;
                    kvc[(size_t)gr * 192 + gc] = f2b(acc[i][j][r]);
                }
    } else {
        // V half -> VbT[bh][dv][s], 8B packed over the 4 consecutive ss (i)
        const int bb = row0 >> 15;                       // uniform per block
        const int ssb = ((row0 >> 4) & (S_ - 1)) + wm * 4;
#pragma unroll
        for (int j = 0; j < 4; j++) {
            const int dv = wn * 64 + j * 16 + col;
#pragma unroll
            for (int r = 0; r < 4; r++) {
                const int hh = quad * 4 + r;
                short4v pk;
#pragma unroll
                for (int i = 0; i < 4; i++) {
                    bf16 v = f2b(acc[i][j][r]);
                    pk[i] = *(short*)&v;
                }
                *(short4v*)&VbT[((size_t)(bb * NH + hh) * 128 + dv) * S_ + ssb] = pk;
            }
        }
    }
}

// ---------------------------------------------------------------------------
// Wave-per-row LN of kv_nope -> bf16 kvn, plus RoPE of k_pe (exp2f freq).
// ---------------------------------------------------------------------------
__global__ __launch_bounds__(256) void kv_ln_k(bf16* __restrict__ kvc,
                                               const float* __restrict__ knw,
                                               const float* __restrict__ knb,
                                               bf16* __restrict__ kvn) {
    const int idx = blockIdx.x * 4 + (threadIdx.x >> 6);   // row 0..65535
    const int lane = threadIdx.x & 63;
    const int s = (idx >> 4) & (S_ - 1);
    const size_t base = (size_t)idx * 192;

    const float v0 = b2f(kvc[base + 64 + lane]);
    const float v1 = b2f(kvc[base + 128 + lane]);
    float xr = 0.f, xi = 0.f;
    if (lane < 32) { xr = b2f(kvc[base + 2 * lane]); xi = b2f(kvc[base + 2 * lane + 1]); }

    float s1 = v0 + v1, s2 = v0 * v0 + v1 * v1;
#pragma unroll
    for (int off = 32; off > 0; off >>= 1) {
        s1 += __shfl_xor(s1, off);
        s2 += __shfl_xor(s2, off);
    }
    const float mu = s1 * (1.f / 128.f);
    const float rinv = rsqrtf(s2 * (1.f / 128.f) - mu * mu + EPSF);
    kvn[(size_t)idx * 128 + lane]      = f2b((v0 - mu) * rinv * knw[lane] + knb[lane]);
    kvn[(size_t)idx * 128 + lane + 64] = f2b((v1 - mu) * rinv * knw[lane + 64] + knb[lane + 64]);

    if (lane < 32) {
        const float freq = exp2f(-0.41524101186092014f * (float)lane); // 10000^(-2l/64)
        const float ang = (float)s * freq;
        float sn, c; sincosf(ang, &sn, &c);
        kvc[base + 128 + 2 * lane]     = f2b(xr * c - xi * sn);
        kvc[base + 128 + 2 * lane + 1] = f2b(xr * sn + xi * c);
    }
}

// ---------------------------------------------------------------------------
// Elementwise fp32 -> bf16 cast.
// ---------------------------------------------------------------------------
__global__ __launch_bounds__(256) void cast_bf16_k(const float* __restrict__ X,
                                                   bf16* __restrict__ Y, int n4) {
    for (int i = blockIdx.x * 256 + threadIdx.x; i < n4; i += gridDim.x * 256) {
        const f32x4 v = ((const f32x4*)X)[i];
        short4v o;
#pragma unroll
        for (int j = 0; j < 4; j++) {
            bf16 b = f2b(v[j]);
            o[j] = *(short*)&b;
        }
        ((short4v*)Y)[i] = o;
    }
}

// ---------------------------------------------------------------------------
// Tiled transpose-cast: W (KxN fp32) -> Wt (NxK bf16).
// ---------------------------------------------------------------------------
__global__ __launch_bounds__(256) void transpose_cast_k(const float* __restrict__ W,
                                                        bf16* __restrict__ Wt,
                                                        int K, int N) {
    __shared__ float tile[32][33];
    const int t = threadIdx.x;
    const int tx = t & 31, ty = t >> 5;
    const int n0 = blockIdx.x * 32;
    const int k0 = blockIdx.y * 32;
#pragma unroll
    for (int i = 0; i < 4; i++)
        tile[ty + 8 * i][tx] = W[(size_t)(k0 + ty + 8 * i) * N + n0 + tx];
    __syncthreads();
#pragma unroll
    for (int i = 0; i < 4; i++)
        Wt[(size_t)(n0 + ty + 8 * i) * K + k0 + tx] = f2b(tile[tx][ty + 8 * i]);
}

// ---------------------------------------------------------------------------
// Row layernorm emitting bf16.
// ---------------------------------------------------------------------------
__global__ __launch_bounds__(256) void layernorm_cast_k(const float* __restrict__ X,
                                                        const float* __restrict__ w,
                                                        const float* __restrict__ b,
                                                        bf16* __restrict__ Y,
                                                        int L) {
    __shared__ float r1[256], r2[256];
    const int row = blockIdx.x;
    const int t = threadIdx.x;
    const float* xp = X + (size_t)row * L;
    bf16* yp = Y + (size_t)row * L;
    float s1 = 0.f, s2 = 0.f;
    for (int j = t; j < L; j += 256) { const float v = xp[j]; s1 += v; s2 += v * v; }
    r1[t] = s1; r2[t] = s2; __syncthreads();
    for (int off = 128; off > 0; off >>= 1) {
        if (t < off) { r1[t] += r1[t + off]; r2[t] += r2[t + off]; }
        __syncthreads();
    }
    const float mu   = r1[0] / (float)L;
    const float var  = r2[0] / (float)L - mu * mu;
    const float rinv = rsqrtf(var + EPSF);
    for (int j = t; j < L; j += 256)
        yp[j] = f2b((xp[j] - mu) * rinv * w[j] + b[j]);
}

// ---------------------------------------------------------------------------
// In-place RoPE on qp (exp2f freq).
// ---------------------------------------------------------------------------
__global__ __launch_bounds__(256) void q_rope_k(bf16* __restrict__ qp) {
    const int total = B_ * S_ * NH * 32;
    for (int p = blockIdx.x * 256 + threadIdx.x; p < total; p += gridDim.x * 256) {
        const int j = p & 31;
        const int row = p >> 5;
        const int sr = row >> 4;
        const int s = sr & (S_ - 1);
        const size_t base = (size_t)row * 192 + 128 + 2 * j;
        const float xr = b2f(qp[base]);
        const float xi = b2f(qp[base + 1]);
        const float freq = exp2f(-0.41524101186092014f * (float)j); // 10000^(-2j/64)
        const float ang = (float)s * freq;
        float sn, c; sincosf(ang, &sn, &c);
        qp[base]     = f2b(xr * c - xi * sn);
        qp[base + 1] = f2b(xr * sn + xi * c);
    }
}

// ---------------------------------------------------------------------------
// Sparse branch (unchanged).
// ---------------------------------------------------------------------------
__global__ __launch_bounds__(256) void sparse_k(const float* __restrict__ gate,
                                                const float* __restrict__ ist,
                                                const float* __restrict__ Wsq,
                                                const float* __restrict__ Wsk,
                                                const float* __restrict__ Wsv,
                                                const float* __restrict__ Wio,
                                                float* __restrict__ io) {
    __shared__ float g[S_];
    __shared__ float sel[TOPK][ID];
    __shared__ float sq[TOPK][ID], sk[TOPK][ID], sv[TOPK][ID];
    __shared__ float sp[TOPK][TOPK];
    __shared__ float ms[ID];
    __shared__ float rv[256];
    __shared__ int ri[256];
    __shared__ int sidx[TOPK];
    const int bi = blockIdx.x;
    const int ih = bi % IH;
    const int b = bi / IH;
    const int t = threadIdx.x;

    for (int s = t; s < S_; s += 256) g[s] = gate[(size_t)(b * S_ + s) * IH + ih];
    __syncthreads();

    for (int r = 0; r < TOPK; r++) {
        float bv = -INFINITY; int bx = S_;
        for (int s = t; s < S_; s += 256) {
            const float v = g[s];
            if (v > bv) { bv = v; bx = s; }
        }
        rv[t] = bv; ri[t] = bx; __syncthreads();
        for (int off = 128; off > 0; off >>= 1) {
            if (t < off) {
                const float v2 = rv[t + off]; const int i2 = ri[t + off];
                if (v2 > rv[t] || (v2 == rv[t] && i2 < ri[t])) { rv[t] = v2; ri[t] = i2; }
            }
            __syncthreads();
        }
        if (t == 0) { sidx[r] = ri[0]; g[ri[0]] = -INFINITY; }
        __syncthreads();
    }

    for (int i = t; i < TOPK * ID; i += 256) {
        const int r = i >> 7, d = i & 127;
        sel[r][d] = ist[((size_t)(b * S_ + sidx[r]) * IH + ih) * ID + d];
    }
    __syncthreads();

    for (int i = t; i < TOPK * ID; i += 256) {
        const int r = i >> 7, n = i & 127;
        float aq = 0.f, ak = 0.f, av = 0.f;
        for (int k = 0; k < 128; k++) {
            const float s = sel[r][k];
            aq += s * Wsq[k * ID + n];
            ak += s * Wsk[k * ID + n];
            av += s * Wsv[k * ID + n];
        }
        sq[r][n] = aq; sk[r][n] = ak; sv[r][n] = av;
    }
    __syncthreads();

    if (t < TOPK * TOPK) {
        const int r = t >> 3, c = t & 7;
        float a = 0.f;
        for (int k = 0; k < 128; k++) a += sq[r][k] * sk[c][k];
        sp[r][c] = a * 0.08838834764831845f;
    }
    __syncthreads();

    if (t < TOPK) {
        float m = -INFINITY;
        for (int c = 0; c < 8; c++) m = fmaxf(m, sp[t][c]);
        float e[8]; float sum = 0.f;
        for (int c = 0; c < 8; c++) { e[c] = expf(sp[t][c] - m); sum += e[c]; }
        for (int c = 0; c < 8; c++) sp[t][c] = e[c] / sum;
    }
    __syncthreads();

    if (t < ID) {
        float acc = 0.f;
        for (int r = 0; r < 8; r++) {
            float so = 0.f;
            for (int c = 0; c < 8; c++) so += sp[r][c] * sv[c][t];
            acc += so;
        }
        ms[t] = acc * 0.125f;
    }
    __syncthreads();

    if (t < ID) {
        float acc = 0.f;
        for (int k = 0; k < 128; k++) acc += ms[k] * Wio[(size_t)k * H_ + t];
        io[((size_t)b * IH + ih) * ID + t] = acc;
    }
}

// ---------------------------------------------------------------------------
// MFMA flash attention v3: as R4 (q-tile pairs, KVBLK=64, setprio, XCD
// swizzle) but V is staged from the TRANSPOSED global layout VbT[bh][dv][s]
// with 4x (short8 load + b128 LDS write) per thread -- replaces the 32
// scalar ds_write_u16 scatter (the R4 bank-conflict hotspot).
// ---------------------------------------------------------------------------
__global__ __launch_bounds__(256) void attn_mfma_k(const bf16* __restrict__ Qp,
                                                   const bf16* __restrict__ Kc,
                                                   const bf16* __restrict__ VbT,
                                                   const float* __restrict__ io,
                                                   bf16* __restrict__ O) {
    __shared__ unsigned short Kt[64 * 200];    // 64 keys x 192 dims (+8 pad)
    __shared__ unsigned short Vt[128 * 72];    // V^T: 128 dv x 64 keys (+8 pad)
    __shared__ unsigned short Ps[4 * 16 * 72]; // per-wave P patch 16q x 64k (+8)
    __shared__ float io_s[128];

    // Chunked XCD swizzle (bijective: 512 = 8 * 64)
    const int lin = blockIdx.x + 16 * blockIdx.y + 256 * blockIdx.z;
    const int swz = (lin & 7) * 64 + (lin >> 3);
    const int pairi = swz & 15;
    const int h = (swz >> 4) & 15;
    const int b = swz >> 8;

    const int t = threadIdx.x;
    const int lane = t & 63;
    const int wq = t >> 6;
    const int col = lane & 15;
    const int quad = lane >> 4;

    if (t < 128) io_s[t] = io[((size_t)b * IH + (h >> 1)) * ID + t];

    const float scale = 0.07216878364870322f;  // 1/sqrt(192)
    const bf16* vplane = VbT + (size_t)(b * NH + h) * 128 * (size_t)S_;

#pragma unroll 1
    for (int ti = 0; ti < 2; ti++) {
        const int qt = (ti == 0) ? pairi : 31 - pairi;
        const int q0 = qt * 64;

        // Q fragments for this tile
        short8 qfrag[6];
        {
            const int q = q0 + wq * 16 + col;
            const short8* qrow = (const short8*)(Qp + ((size_t)(b * S_ + q) * NH + h) * 192);
#pragma unroll
            for (int kc = 0; kc < 6; kc++) qfrag[kc] = qrow[kc * 4 + quad];
        }

        float m_r[4], l_r[4];
#pragma unroll
        for (int r = 0; r < 4; r++) { m_r[r] = -1e30f; l_r[r] = 0.f; }
        f32x4 accO[8];
#pragma unroll
        for (int nt = 0; nt < 8; nt++) accO[nt] = (f32x4){0.f, 0.f, 0.f, 0.f};

        const int nkt = qt + 1;   // 64-key tiles: keys 0 .. (qt+1)*64-1

        for (int kt = 0; kt < nkt; kt++) {
            const int kt0 = kt * 64;
            __syncthreads();   // protect Kt/Vt/Ps from previous readers
            // Stage K-tile: 64 rows x 192 bf16. Thread t: row t>>2, 48-col chunk.
            {
                const int kr = t >> 2;
                const int c0 = (t & 3) * 48;
                const short8* src = (const short8*)(Kc + ((size_t)(b * S_ + kt0 + kr) * NH + h) * 192 + c0);
                short8* dst = (short8*)&Kt[kr * 200 + c0];
#pragma unroll
                for (int c = 0; c < 6; c++) dst[c] = src[c];
            }
            // Stage V-tile from VbT: rows = dv, 64 contiguous ki. b128 in/out.
            {
                const int ki0 = (t & 7) * 8;
#pragma unroll
                for (int p = 0; p < 4; p++) {
                    const int dv = p * 32 + (t >> 3);
                    const short8 vv = *(const short8*)(vplane + (size_t)dv * S_ + kt0 + ki0);
                    *(short8*)&Vt[dv * 72 + ki0] = vv;
                }
            }
            __syncthreads();

            // Scores: four 16-key n-tiles, K=192 in 6 mfma steps each.
            f32x4 s[4];
            __builtin_amdgcn_s_setprio(1);
#pragma unroll
            for (int nt = 0; nt < 4; nt++) {
                f32x4 acc = (f32x4){0.f, 0.f, 0.f, 0.f};
#pragma unroll
                for (int kc = 0; kc < 6; kc++) {
                    const short8 kf = *(const short8*)&Kt[(nt * 16 + col) * 200 + kc * 32 + quad * 8];
                    acc = __builtin_amdgcn_mfma_f32_16x16x32_bf16(qfrag[kc], kf, acc, 0, 0, 0);
                }
                s[nt] = acc;
            }
            __builtin_amdgcn_s_setprio(0);
            // Scale + causal mask
#pragma unroll
            for (int nt = 0; nt < 4; nt++)
#pragma unroll
                for (int r = 0; r < 4; r++) {
                    const int kg = kt0 + nt * 16 + col;
                    const int qg = q0 + wq * 16 + quad * 4 + r;
                    const float v = s[nt][r] * scale;
                    s[nt][r] = (kg > qg) ? -1e30f : v;
                }
            // Online softmax per query row
            float alpha[4];
#pragma unroll
            for (int r = 0; r < 4; r++) {
                float mt = fmaxf(fmaxf(s[0][r], s[1][r]), fmaxf(s[2][r], s[3][r]));
                mt = fmaxf(mt, __shfl_xor(mt, 1));
                mt = fmaxf(mt, __shfl_xor(mt, 2));
                mt = fmaxf(mt, __shfl_xor(mt, 4));
                mt = fmaxf(mt, __shfl_xor(mt, 8));
                const float mn = fmaxf(m_r[r], mt);
                alpha[r] = __expf(m_r[r] - mn);
                m_r[r] = mn;
                float rs = 0.f;
#pragma unroll
                for (int nt = 0; nt < 4; nt++) {
                    const float p = __expf(s[nt][r] - mn);
                    s[nt][r] = p;
                    rs += p;
                }
                rs += __shfl_xor(rs, 1);
                rs += __shfl_xor(rs, 2);
                rs += __shfl_xor(rs, 4);
                rs += __shfl_xor(rs, 8);
                l_r[r] = l_r[r] * alpha[r] + rs;
            }
            // P (C-layout) -> bf16 LDS -> reread in A-layout (per-wave region).
            {
                unsigned short* pw = &Ps[wq * 1152];
#pragma unroll
                for (int nt = 0; nt < 4; nt++)
#pragma unroll
                    for (int r = 0; r < 4; r++) {
                        bf16 hv = f2b(s[nt][r]);
                        pw[(quad * 4 + r) * 72 + nt * 16 + col] = *(unsigned short*)&hv;
                    }
            }
            short8 pf[2];
#pragma unroll
            for (int kk = 0; kk < 2; kk++)
                pf[kk] = *(const short8*)&Ps[wq * 1152 + col * 72 + kk * 32 + quad * 8];
            // Rescale O, then accumulate P.V (k = 64 in two 32-steps).
#pragma unroll
            for (int nt = 0; nt < 8; nt++)
#pragma unroll
                for (int r = 0; r < 4; r++) accO[nt][r] *= alpha[r];
            __builtin_amdgcn_s_setprio(1);
#pragma unroll
            for (int nt = 0; nt < 8; nt++) {
#pragma unroll
                for (int kk = 0; kk < 2; kk++) {
                    const short8 vf = *(const short8*)&Vt[(nt * 16 + col) * 72 + kk * 32 + quad * 8];
                    accO[nt] = __builtin_amdgcn_mfma_f32_16x16x32_bf16(pf[kk], vf, accO[nt], 0, 0, 0);
                }
            }
            __builtin_amdgcn_s_setprio(0);
        }

        // Epilogue for this tile
        float rinv[4];
#pragma unroll
        for (int r = 0; r < 4; r++) rinv[r] = 1.f / l_r[r];
#pragma unroll
        for (int nt = 0; nt < 8; nt++) {
            const int dv = nt * 16 + col;
            const float iov = io_s[dv];
#pragma unroll
            for (int r = 0; r < 4; r++) {
                const int q = q0 + wq * 16 + quad * 4 + r;
                O[((size_t)(b * S_ + q) * NH + h) * VD + dv] = f2b(accO[nt][r] * rinv[r] + iov);
            }
        }
    }
}

// ---------------------------------------------------------------------------
// Workspace lifetime plan (within proven ~100.8 MB):
//   rbig @0 (33.5MB): cq fp32 -> { ist fp32 [0,16M) ; kvn bf16 [16M,32M) }
//                      -> attnb bf16 [0,16M)
//   qp   @32MB (25.2MB)
//   kvc  @56MB (25.2MB): cq_bf16 (pre-kvc) -> kvc
//   VbT/Wt @80MB (16.8MB): Wt transposes -> VbT (transposed V) -> Wt(W_o)
//   gate @96MB (131KB): gate -> WkvT (64KB, post-sparse)
//   iob  @96MB+128KB
//   x_bf16 lives in d_out (dead before the final GEMM writes out).
// ---------------------------------------------------------------------------
extern "C" void kernel_launch(void* const* d_in, const int* in_sizes, int n_in,
                              void* d_out, int out_size, void* d_ws, size_t ws_size,
                              hipStream_t stream) {
    const float* x      = (const float*)d_in[0];
    const float* W_cq   = (const float*)d_in[1];
    const float* qn_w   = (const float*)d_in[2];
    const float* qn_b   = (const float*)d_in[3];
    const float* W_q    = (const float*)d_in[4];
    const float* W_ckv  = (const float*)d_in[5];
    const float* kvn_w  = (const float*)d_in[6];
    const float* kvn_b  = (const float*)d_in[7];
    const float* W_kv   = (const float*)d_in[8];
    const float* W_o    = (const float*)d_in[9];
    const float* W_ip   = (const float*)d_in[10];
    const float* W_ig   = (const float*)d_in[11];
    const float* W_sq   = (const float*)d_in[12];
    const float* W_sk   = (const float*)d_in[13];
    const float* W_sv   = (const float*)d_in[14];
    const float* W_io   = (const float*)d_in[15];
    float* out = (float*)d_out;

    const int M = B_ * S_;

    char* wsb = (char*)d_ws;
    float* rbig  = (float*)wsb;
    bf16*  kvn   = (bf16*)(wsb + 16777216);   // upper half of rbig
    bf16*  qp    = (bf16*)(wsb + 33554432);
    bf16*  kvc   = (bf16*)(wsb + 58720256);
    bf16*  cqb   = (bf16*)(wsb + 58720256);   // alias kvc (dead before kvc)
    bf16*  VbT   = (bf16*)(wsb + 83886080);
    bf16*  Wt    = (bf16*)(wsb + 83886080);   // alias VbT (disjoint lifetimes)
    float* gate  = (float*)(wsb + 100663296);
    bf16*  WkvT  = (bf16*)(wsb + 100663296);  // alias gate (post-sparse)
    float* iob   = (float*)(wsb + 100794368);
    float* cq    = rbig;
    float* ist   = rbig;
    bf16*  attnb = (bf16*)rbig;
    bf16*  xb    = (bf16*)d_out;              // x_bf16 in output buffer

    dim3 blk(256);

    // Stage 0: casts
    cast_bf16_k<<<dim3(2048), blk, 0, stream>>>(x, xb, M * H_ / 4);

    // qc = LN(x @ W_cq)
    transpose_cast_k<<<dim3(QLR / 32, H_ / 32), blk, 0, stream>>>(W_cq, Wt, H_, QLR);
    gemm_bt_mfma_k<float><<<dim3(QLR / 128, M / 128), blk, 0, stream>>>(xb, Wt, cq, M, QLR, H_);
    layernorm_cast_k<<<dim3(M), blk, 0, stream>>>(cq, qn_w, qn_b, cqb, QLR);

    // qp = qc @ W_q
    transpose_cast_k<<<dim3(3072 / 32, QLR / 32), blk, 0, stream>>>(W_q, Wt, QLR, 3072);
    gemm_bt_mfma_k<bf16><<<dim3(3072 / 128, M / 128), blk, 0, stream>>>(cqb, Wt, qp, M, 3072, QLR);

    // kvc = x @ W_ckv
    transpose_cast_k<<<dim3(3072 / 32, H_ / 32), blk, 0, stream>>>(W_ckv, Wt, H_, 3072);
    gemm_bt_mfma_k<bf16><<<dim3(3072 / 128, M / 128), blk, 0, stream>>>(xb, Wt, kvc, M, 3072, H_);

    // ist = x @ W_ip (fp32 out for sparse branch)
    transpose_cast_k<<<dim3(1024 / 32, H_ / 32), blk, 0, stream>>>(W_ip, Wt, H_, 1024);
    gemm_bt_mfma_k<float><<<dim3(1024 / 128, M / 128), blk, 0, stream>>>(xb, Wt, ist, M, IH * ID, H_);

    // gate = x @ W_ig — EXACT fp32 (top-k index stability)
    gate_k<<<dim3(M / 4), blk, 0, stream>>>(x, W_ig, gate);

    q_rope_k<<<dim3(2048), blk, 0, stream>>>(qp);

    // KV path: LN+RoPE (wave-per-row) -> bf16 kvn; then MFMA matmul w/ scatter.
    kv_ln_k<<<dim3(B_ * S_ * NH / 4), blk, 0, stream>>>(kvc, kvn_w, kvn_b, kvn);

    sparse_k<<<dim3(B_ * IH), blk, 0, stream>>>(gate, ist, W_sq, W_sk, W_sv, W_io, iob);

    // Wkv^T (128x256 fp32 -> 256x128 bf16) into dead gate buffer
    transpose_cast_k<<<dim3(256 / 32, 128 / 32), blk, 0, stream>>>(W_kv, WkvT, 128, 256);
    gemm_kv_k<<<dim3(2, (B_ * S_ * NH) / 128), blk, 0, stream>>>(kvn, WkvT, kvc, VbT);

    // attention -> bf16 attn (rbig; ist/kvn already consumed)
    attn_mfma_k<<<dim3(16, NH, B_), blk, 0, stream>>>(qp, kvc, VbT, iob, attnb);

    // out = attn @ W_o (VbT dead -> reuse for W_o^T)
    transpose_cast_k<<<dim3(H_ / 32, H_ / 32), blk, 0, stream>>>(W_o, Wt, H_, H_);
    gemm_bt_mfma_k<float><<<dim3(H_ / 128, M / 128), blk, 0, stream>>>(attnb, Wt, out, M, H_, H_);
}